// Round 9
// baseline (292.734 us; speedup 1.0000x reference)
//
#include <hip/hip_runtime.h>

typedef unsigned short ushort_t;
typedef __attribute__((ext_vector_type(8))) short short8;   // 8 bf16 (4 VGPRs)
typedef __attribute__((ext_vector_type(4))) float floatx4;  // 4 fp32 acc

#define DEV static __device__ __forceinline__
#define NEG_BIG (-1e30f)

typedef const __attribute__((address_space(1))) unsigned int* gas_ptr;
typedef __attribute__((address_space(3))) unsigned int* las_ptr;

// async global->LDS, 16B per lane; LDS dest = base + lane*16 (wave-uniform base)
DEV void async16(const ushort_t* g, ushort_t* l) {
    __builtin_amdgcn_global_load_lds((gas_ptr)(const void*)g, (las_ptr)(void*)l, 16, 0, 0);
}

DEV float bf2f(ushort_t u) {
    union { unsigned u; float f; } v; v.u = ((unsigned)u) << 16; return v.f;
}
DEV ushort_t f2bf(float f) {
    union { float f; unsigned u; } v; v.f = f;
    unsigned r = v.u + 0x7FFF + ((v.u >> 16) & 1);   // RNE
    return (ushort_t)(r >> 16);
}
DEV float load_bf16_scrub(const ushort_t* p, size_t i) {
    ushort_t u = p[i];
    if (((u >> 7) & 0xFF) == 0xFF) u = 0;
    return bf2f(u);
}
DEV float load_f32_scrub(const ushort_t* p, size_t i) {
    unsigned u = ((const unsigned*)p)[i];
    if (((u >> 23) & 0xFF) == 0xFF) u = 0;
    union { unsigned u; float f; } v; v.u = u; return v.f;
}

// Probe: fp32 vs bf16 raw data (proven in R3/R4). Block-uniform result.
DEV int probe_is_f32(const ushort_t* __restrict__ p) {
    int tid = threadIdx.x + threadIdx.y * blockDim.x;
    int nthr = blockDim.x * blockDim.y;
    __shared__ int cnt;
    if (tid == 0) cnt = 0;
    __syncthreads();
    int weird = 0;
    for (int i = tid; i < 2048; i += nthr) {
        unsigned e = (p[i] >> 7) & 0xFF;
        weird += (e >= 0x90) ? 1 : 0;
    }
#pragma unroll
    for (int off = 32; off; off >>= 1) weird += __shfl_xor(weird, off);
    if ((tid & 63) == 0) atomicAdd(&cnt, weird);
    __syncthreads();
    return cnt > 16;
}

// ---------------------------------------------------------------- RMSNorm ---
__global__ void rmsnorm_kernel(const ushort_t* __restrict__ x,
                               const ushort_t* __restrict__ g,
                               ushort_t* __restrict__ xn) {
    int is_f32 = probe_is_f32(x);
    int row = blockIdx.x;
    int tid = threadIdx.x;
    float vals[4], gv[4];
    size_t base = (size_t)row * 1024 + tid * 4;
#pragma unroll
    for (int i = 0; i < 4; i++) {
        if (is_f32) {
            vals[i] = load_f32_scrub(x, base + i);
            gv[i]   = load_f32_scrub(g, tid * 4 + i);
        } else {
            vals[i] = load_bf16_scrub(x, base + i);
            gv[i]   = load_bf16_scrub(g, tid * 4 + i);
        }
    }
    float ss = vals[0]*vals[0] + vals[1]*vals[1] + vals[2]*vals[2] + vals[3]*vals[3];
#pragma unroll
    for (int off = 32; off > 0; off >>= 1) ss += __shfl_xor(ss, off);
    __shared__ float red[4];
    if ((tid & 63) == 0) red[tid >> 6] = ss;
    __syncthreads();
    ss = red[0] + red[1] + red[2] + red[3];
    float inv = rsqrtf(ss * (1.0f / 1024.0f) + 1e-6f);
#pragma unroll
    for (int i = 0; i < 4; i++)
        xn[base + i] = f2bf(vals[i] * inv * gv[i]);
}

// ------------------------------------------------------- weight transpose ---
__global__ void transpose_qkv(const ushort_t* __restrict__ W0,
                              const ushort_t* __restrict__ W1,
                              const ushort_t* __restrict__ W2,
                              ushort_t* __restrict__ Wt,
                              const ushort_t* __restrict__ probe) {
    int is_f32 = probe_is_f32(probe);
    const ushort_t* W = (blockIdx.z == 0) ? W0 : (blockIdx.z == 1) ? W1 : W2;
    __shared__ ushort_t tile[32][33];
    int tx = threadIdx.x, ty = threadIdx.y;
    int x = blockIdx.x * 32 + tx;       // n
    int y0 = blockIdx.y * 32;           // k
#pragma unroll
    for (int j = 0; j < 32; j += 8) {
        size_t idx = (size_t)(y0 + ty + j) * 1024 + x;
        tile[ty + j][tx] = f2bf(is_f32 ? load_f32_scrub(W, idx) : load_bf16_scrub(W, idx));
    }
    __syncthreads();
    int nx = blockIdx.y * 32 + tx;
    int ny0 = blockIdx.x * 32 + blockIdx.z * 1024;
#pragma unroll
    for (int j = 0; j < 32; j += 8) Wt[(size_t)(ny0 + ty + j) * 1024 + nx] = tile[tx][ty + j];
}

__global__ void transpose_w(const ushort_t* __restrict__ W, ushort_t* __restrict__ Wt,
                            const ushort_t* __restrict__ probe) {
    int is_f32 = probe_is_f32(probe);
    __shared__ ushort_t tile[32][33];
    int tx = threadIdx.x, ty = threadIdx.y;
    int x = blockIdx.x * 32 + tx;
    int y0 = blockIdx.y * 32;
#pragma unroll
    for (int j = 0; j < 32; j += 8) {
        size_t idx = (size_t)(y0 + ty + j) * 1024 + x;
        tile[ty + j][tx] = f2bf(is_f32 ? load_f32_scrub(W, idx) : load_bf16_scrub(W, idx));
    }
    __syncthreads();
    int nx = blockIdx.y * 32 + tx;
    int ny0 = blockIdx.x * 32;
#pragma unroll
    for (int j = 0; j < 32; j += 8) Wt[(size_t)(ny0 + ty + j) * 1024 + nx] = tile[tx][ty + j];
}

// ------------------------------------------------------------------- GEMM ---
// 128x128 block tile, BK=64, async staging into fragment-ordered LDS where
// staging lane L holds exactly reading lane L's 16B (row L&15, kchunk L>>4)
// -> ds_read_b128 is lane-linear, zero bank conflicts. 4 waves, wave tile
// 64x64 (acc 4x4), 32 MFMA per wave per k-step, 16 k-steps.
// XCD swizzle: lin%8 = XCD; each XCD gets an 8m x XN-block region.
// MODE 0: QKV routing epilogue; MODE 1: fp32 C store.
template <int MODE>
__global__ __launch_bounds__(256) void gemm_m97(const ushort_t* __restrict__ A,
                                                const ushort_t* __restrict__ Bt,
                                                ushort_t* __restrict__ qb,
                                                ushort_t* __restrict__ kb,
                                                ushort_t* __restrict__ vt,
                                                float* __restrict__ C) {
    const int K = 1024;
    int tid = threadIdx.x;
    int lane = tid & 63, w = tid >> 6;
    int c = lane & 15, quad = lane >> 4;
    int mh = w >> 1, nh = w & 1;
    // XCD-region swizzle (grid.x * grid.y must be a multiple of 64)
    int lin = blockIdx.y * gridDim.x + blockIdx.x;
    int xcd = lin & 7, idx = lin >> 3;
    int XN = (gridDim.x * gridDim.y) >> 6;          // n-blocks per XCD region
    int bm = ((xcd & 3) * 8 + (idx & 7)) * 128;
    int bn = ((xcd >> 2) * XN + (idx >> 3)) * 128;
    int srow = lane & 15, skc = lane >> 4;          // staging lane -> (row, kchunk)

    __shared__ __align__(16) ushort_t As[16 * 512];
    __shared__ __align__(16) ushort_t Bs[16 * 512];

    const floatx4 zero = {0.f, 0.f, 0.f, 0.f};
    floatx4 acc[4][4];
#pragma unroll
    for (int i = 0; i < 4; i++)
#pragma unroll
        for (int j = 0; j < 4; j++) acc[i][j] = zero;

    for (int k0 = 0; k0 < K; k0 += 64) {
        __syncthreads();
#pragma unroll
        for (int ci = 0; ci < 8; ci++) {
            int ch = w * 8 + ci;          // 0..31; wave-uniform routing
            if (ch < 16) {
                int rg = ch >> 1, kc = ch & 1;
                async16(A + (size_t)(bm + rg * 16 + srow) * K + k0 + kc * 32 + skc * 8,
                        As + ch * 512);
            } else {
                int b2 = ch - 16;
                int rg = b2 >> 1, kc = b2 & 1;
                async16(Bt + (size_t)(bn + rg * 16 + srow) * K + k0 + kc * 32 + skc * 8,
                        Bs + b2 * 512);
            }
        }
        __syncthreads();
#pragma unroll
        for (int kc = 0; kc < 2; kc++) {
            short8 af[4], bf[4];
#pragma unroll
            for (int i = 0; i < 4; i++)
                af[i] = *(const short8*)(As + ((mh * 4 + i) * 2 + kc) * 512 + lane * 8);
#pragma unroll
            for (int j = 0; j < 4; j++)
                bf[j] = *(const short8*)(Bs + ((nh * 4 + j) * 2 + kc) * 512 + lane * 8);
#pragma unroll
            for (int i = 0; i < 4; i++)
#pragma unroll
                for (int j = 0; j < 4; j++)
                    acc[i][j] = __builtin_amdgcn_mfma_f32_16x16x32_bf16(af[i], bf[j], acc[i][j], 0, 0, 0);
        }
    }

    if (MODE == 0) {
        int proj = bn >> 10;                 // 0=q, 1=k, 2=v (blocks never straddle)
        int n0 = (bn & 1023) + nh * 64;
        if (proj < 2) {                      // RoPE: d = j*16+c, pairs (j, j+2)
            float th0 = exp2f((float)c * (-19.931568569324174f / 32.0f));
            float th1 = exp2f((float)(16 + c) * (-19.931568569324174f / 32.0f));
            float scale = (proj == 0) ? 0.125f : 1.0f;
#pragma unroll
            for (int i = 0; i < 4; i++)
#pragma unroll
                for (int r = 0; r < 4; r++) {
                    int s = (bm + mh * 64 + i * 16 + quad * 4 + r) & 2047;
                    float sn0, cs0, sn1, cs1;
                    sincosf((float)s * th0, &sn0, &cs0);
                    sincosf((float)s * th1, &sn1, &cs1);
                    float x1a = acc[i][0][r], x2a = acc[i][2][r];
                    acc[i][0][r] = (x1a * cs0 - x2a * sn0) * scale;
                    acc[i][2][r] = (x1a * sn0 + x2a * cs0) * scale;
                    float x1b = acc[i][1][r], x2b = acc[i][3][r];
                    acc[i][1][r] = (x1b * cs1 - x2b * sn1) * scale;
                    acc[i][3][r] = (x1b * sn1 + x2b * cs1) * scale;
                }
        }
        ushort_t* dst = (proj == 0) ? qb : kb;
#pragma unroll
        for (int i = 0; i < 4; i++)
#pragma unroll
            for (int j = 0; j < 4; j++)
#pragma unroll
                for (int r = 0; r < 4; r++) {
                    int row = bm + mh * 64 + i * 16 + quad * 4 + r;
                    int col = n0 + j * 16 + c;
                    if (proj == 2) {
                        int b = row >> 11, s = row & 2047;
                        int hh = col >> 6, dh = col & 63;
                        vt[(size_t)((b * 16 + hh) * 64 + dh) * 2048 + s] = f2bf(acc[i][j][r]);
                    } else {
                        dst[(size_t)row * 1024 + col] = f2bf(acc[i][j][r]);
                    }
                }
    } else {
#pragma unroll
        for (int i = 0; i < 4; i++)
#pragma unroll
            for (int j = 0; j < 4; j++)
#pragma unroll
                for (int r = 0; r < 4; r++) {
                    int row = bm + mh * 64 + i * 16 + quad * 4 + r;
                    int col = bn + nh * 64 + j * 16 + c;
                    C[(size_t)row * 1024 + col] = acc[i][j][r];
                }
    }
}

// -------------------------------------------------------------- attention ---
// grid (bh=32, pair=16): same-(b,h) blocks share XCD. Uniform pairing
// (qt, 31-qt) = 33 key-tiles/block. K/V staged async, fragment-ordered with
// conflict-free lane mapping (staging lane L = reading lane L).
__global__ __launch_bounds__(256) void attn_kernel(const ushort_t* __restrict__ q,
                                                   const ushort_t* __restrict__ k,
                                                   const ushort_t* __restrict__ vt,
                                                   ushort_t* __restrict__ o) {
    int tid = threadIdx.x;
    int lane = tid & 63, w = tid >> 6;
    int c = lane & 15, quad = lane >> 4;
    int bh = blockIdx.x;
    int b = bh >> 4, h = bh & 15;
    int pair = blockIdx.y;              // 0..15
    int srow = lane & 15, skc = lane >> 4;
    const ushort_t* qb  = q + (size_t)b * 2048 * 1024 + h * 64;
    const ushort_t* kbp = k + (size_t)b * 2048 * 1024 + h * 64;
    const ushort_t* vtb = vt + (size_t)(b * 16 + h) * 64 * 2048;
    ushort_t* ob = o + (size_t)b * 2048 * 1024 + h * 64;

    __shared__ __align__(16) ushort_t Ks[8 * 512];
    __shared__ __align__(16) ushort_t Vs[8 * 512];
    __shared__ __align__(16) ushort_t Ps[64 * 72];

    const floatx4 zero = {0.f, 0.f, 0.f, 0.f};

#pragma unroll
    for (int g = 0; g < 2; g++) {
        int qt  = g ? (31 - pair) : pair;
        int t0b = qt * 64;
        int t0w = t0b + w * 16;
        int ntile = qt + 1;

        const ushort_t* qrow = qb + (size_t)(t0w + c) * 1024;
        short8 aq0 = *(const short8*)(qrow + quad * 8);
        short8 aq1 = *(const short8*)(qrow + 32 + quad * 8);

        float l_part[4];
        floatx4 oacc[4];
#pragma unroll
        for (int r = 0; r < 4; r++) l_part[r] = 0.f;
#pragma unroll
        for (int dt = 0; dt < 4; dt++) oacc[dt] = zero;

        for (int kt = 0; kt < ntile; kt++) {
            int s0 = kt * 64;
            __syncthreads();     // protect Ks/Vs from previous tile's readers
#pragma unroll
            for (int ci = 0; ci < 4; ci++) {
                int ch = w * 4 + ci;
                if (ch < 8) {
                    int nt = ch >> 1, hf = ch & 1;
                    async16(kbp + (size_t)(s0 + nt * 16 + srow) * 1024 + hf * 32 + skc * 8,
                            Ks + ch * 512);
                } else {
                    int dt = (ch - 8) >> 1, hf = ch & 1;
                    async16(vtb + (size_t)(dt * 16 + srow) * 2048 + s0 + hf * 32 + skc * 8,
                            Vs + (ch - 8) * 512);
                }
            }
            __syncthreads();

            floatx4 sacc[4];
#pragma unroll
            for (int nt = 0; nt < 4; nt++) sacc[nt] = zero;
#pragma unroll
            for (int nt = 0; nt < 4; nt++) {
                short8 b0 = *(const short8*)(Ks + (nt * 2) * 512 + lane * 8);
                short8 b1 = *(const short8*)(Ks + (nt * 2 + 1) * 512 + lane * 8);
                sacc[nt] = __builtin_amdgcn_mfma_f32_16x16x32_bf16(aq0, b0, sacc[nt], 0, 0, 0);
                sacc[nt] = __builtin_amdgcn_mfma_f32_16x16x32_bf16(aq1, b1, sacc[nt], 0, 0, 0);
            }

            if (kt == ntile - 1) {   // diagonal tile: causal mask
#pragma unroll
                for (int r = 0; r < 4; r++) {
                    int t = t0w + quad * 4 + r;
                    float ps = 0.f;
#pragma unroll
                    for (int nt = 0; nt < 4; nt++) {
                        float v = (s0 + nt * 16 + c > t) ? NEG_BIG : sacc[nt][r];
                        float e = __expf(v);
                        ps += e;
                        Ps[(w * 16 + quad * 4 + r) * 72 + nt * 16 + c] = f2bf(e);
                    }
                    l_part[r] += ps;
                }
            } else {
#pragma unroll
                for (int r = 0; r < 4; r++) {
                    float ps = 0.f;
#pragma unroll
                    for (int nt = 0; nt < 4; nt++) {
                        float e = __expf(sacc[nt][r]);
                        ps += e;
                        Ps[(w * 16 + quad * 4 + r) * 72 + nt * 16 + c] = f2bf(e);
                    }
                    l_part[r] += ps;
                }
            }

            short8 pa0 = *(const short8*)(Ps + (w * 16 + c) * 72 + quad * 8);
            short8 pa1 = *(const short8*)(Ps + (w * 16 + c) * 72 + 32 + quad * 8);
#pragma unroll
            for (int dt = 0; dt < 4; dt++) {
                short8 v0 = *(const short8*)(Vs + (dt * 2) * 512 + lane * 8);
                short8 v1 = *(const short8*)(Vs + (dt * 2 + 1) * 512 + lane * 8);
                oacc[dt] = __builtin_amdgcn_mfma_f32_16x16x32_bf16(pa0, v0, oacc[dt], 0, 0, 0);
                oacc[dt] = __builtin_amdgcn_mfma_f32_16x16x32_bf16(pa1, v1, oacc[dt], 0, 0, 0);
            }
        }

        float linv[4];
#pragma unroll
        for (int r = 0; r < 4; r++) {
            float l = l_part[r];
#pragma unroll
            for (int off = 1; off < 16; off <<= 1) l += __shfl_xor(l, off);
            linv[r] = 1.0f / l;
        }
#pragma unroll
        for (int dt = 0; dt < 4; dt++)
#pragma unroll
            for (int r = 0; r < 4; r++) {
                int t = t0w + quad * 4 + r;
                ob[(size_t)t * 1024 + dt * 16 + c] = f2bf(oacc[dt][r] * linv[r]);
            }
    }
}

// ------------------------------------------------------------------ launch ---
extern "C" void kernel_launch(void* const* d_in, const int* in_sizes, int n_in,
                              void* d_out, int out_size, void* d_ws, size_t ws_size,
                              hipStream_t stream) {
    const ushort_t* x  = (const ushort_t*)d_in[0];
    const ushort_t* g  = (const ushort_t*)d_in[1];
    const ushort_t* Wq = (const ushort_t*)d_in[2];
    const ushort_t* Wk = (const ushort_t*)d_in[3];
    const ushort_t* Wv = (const ushort_t*)d_in[4];
    const ushort_t* Wo = (const ushort_t*)d_in[5];

    char* ws = (char*)d_ws;
    const size_t MB = 1ull << 20;
    ushort_t* xn   = (ushort_t*)(ws);            // 8 MB (reused as attn out)
    ushort_t* qb   = (ushort_t*)(ws + 8 * MB);   // 8 MB
    ushort_t* kb   = (ushort_t*)(ws + 16 * MB);  // 8 MB
    ushort_t* vt   = (ushort_t*)(ws + 24 * MB);  // 8 MB ([b,h,dh,s])
    ushort_t* WTq3 = (ushort_t*)(ws + 32 * MB);  // 6 MB (q|k|v transposed)
    ushort_t* WoT  = (ushort_t*)(ws + 38 * MB);  // 2 MB  -> total 40 MB
    ushort_t* at   = xn;

    dim3 tb(32, 8);
    rmsnorm_kernel<<<4096, 256, 0, stream>>>(x, g, xn);
    transpose_qkv<<<dim3(32, 32, 3), tb, 0, stream>>>(Wq, Wk, Wv, WTq3, x);
    transpose_w<<<dim3(32, 32), tb, 0, stream>>>(Wo, WoT, x);

    gemm_m97<0><<<dim3(24, 32), 256, 0, stream>>>(xn, WTq3, qb, kb, vt, nullptr);

    attn_kernel<<<dim3(32, 16), 256, 0, stream>>>(qb, kb, vt, at);

    gemm_m97<1><<<dim3(8, 32), 256, 0, stream>>>(at, WoT, nullptr, nullptr, nullptr, (float*)d_out);
}

// Round 10
// 226.966 us; speedup vs baseline: 1.2898x; 1.2898x over previous
//
#include <hip/hip_runtime.h>

typedef unsigned short ushort_t;
typedef __attribute__((ext_vector_type(8))) short short8;   // 8 bf16 (4 VGPRs)
typedef __attribute__((ext_vector_type(4))) float floatx4;  // 4 fp32 acc

#define DEV static __device__ __forceinline__
#define NEG_BIG (-1e30f)

typedef const __attribute__((address_space(1))) unsigned int* gas_ptr;
typedef __attribute__((address_space(3))) unsigned int* las_ptr;

// async global->LDS, 16B per lane; LDS dest = base + lane*16 (wave-uniform base)
DEV void async16(const ushort_t* g, ushort_t* l) {
    __builtin_amdgcn_global_load_lds((gas_ptr)(const void*)g, (las_ptr)(void*)l, 16, 0, 0);
}

DEV float bf2f(ushort_t u) {
    union { unsigned u; float f; } v; v.u = ((unsigned)u) << 16; return v.f;
}
DEV ushort_t f2bf(float f) {
    union { float f; unsigned u; } v; v.f = f;
    unsigned r = v.u + 0x7FFF + ((v.u >> 16) & 1);   // RNE
    return (ushort_t)(r >> 16);
}
DEV float load_bf16_scrub(const ushort_t* p, size_t i) {
    ushort_t u = p[i];
    if (((u >> 7) & 0xFF) == 0xFF) u = 0;
    return bf2f(u);
}
DEV float load_f32_scrub(const ushort_t* p, size_t i) {
    unsigned u = ((const unsigned*)p)[i];
    if (((u >> 23) & 0xFF) == 0xFF) u = 0;
    union { unsigned u; float f; } v; v.u = u; return v.f;
}

// Probe: fp32 vs bf16 raw data (proven in R3/R4). Block-uniform result.
DEV int probe_is_f32(const ushort_t* __restrict__ p) {
    int tid = threadIdx.x + threadIdx.y * blockDim.x;
    int nthr = blockDim.x * blockDim.y;
    __shared__ int cnt;
    if (tid == 0) cnt = 0;
    __syncthreads();
    int weird = 0;
    for (int i = tid; i < 2048; i += nthr) {
        unsigned e = (p[i] >> 7) & 0xFF;
        weird += (e >= 0x90) ? 1 : 0;
    }
#pragma unroll
    for (int off = 32; off; off >>= 1) weird += __shfl_xor(weird, off);
    if ((tid & 63) == 0) atomicAdd(&cnt, weird);
    __syncthreads();
    return cnt > 16;
}

// ---------------------------------------------------------------- RMSNorm ---
__global__ void rmsnorm_kernel(const ushort_t* __restrict__ x,
                               const ushort_t* __restrict__ g,
                               ushort_t* __restrict__ xn) {
    int is_f32 = probe_is_f32(x);
    int row = blockIdx.x;
    int tid = threadIdx.x;
    float vals[4], gv[4];
    size_t base = (size_t)row * 1024 + tid * 4;
#pragma unroll
    for (int i = 0; i < 4; i++) {
        if (is_f32) {
            vals[i] = load_f32_scrub(x, base + i);
            gv[i]   = load_f32_scrub(g, tid * 4 + i);
        } else {
            vals[i] = load_bf16_scrub(x, base + i);
            gv[i]   = load_bf16_scrub(g, tid * 4 + i);
        }
    }
    float ss = vals[0]*vals[0] + vals[1]*vals[1] + vals[2]*vals[2] + vals[3]*vals[3];
#pragma unroll
    for (int off = 32; off > 0; off >>= 1) ss += __shfl_xor(ss, off);
    __shared__ float red[4];
    if ((tid & 63) == 0) red[tid >> 6] = ss;
    __syncthreads();
    ss = red[0] + red[1] + red[2] + red[3];
    float inv = rsqrtf(ss * (1.0f / 1024.0f) + 1e-6f);
#pragma unroll
    for (int i = 0; i < 4; i++)
        xn[base + i] = f2bf(vals[i] * inv * gv[i]);
}

// ------------------------------------------------------- weight transpose ---
__global__ void transpose_qkv(const ushort_t* __restrict__ W0,
                              const ushort_t* __restrict__ W1,
                              const ushort_t* __restrict__ W2,
                              ushort_t* __restrict__ Wt,
                              const ushort_t* __restrict__ probe) {
    int is_f32 = probe_is_f32(probe);
    const ushort_t* W = (blockIdx.z == 0) ? W0 : (blockIdx.z == 1) ? W1 : W2;
    __shared__ ushort_t tile[32][33];
    int tx = threadIdx.x, ty = threadIdx.y;
    int x = blockIdx.x * 32 + tx;       // n
    int y0 = blockIdx.y * 32;           // k
#pragma unroll
    for (int j = 0; j < 32; j += 8) {
        size_t idx = (size_t)(y0 + ty + j) * 1024 + x;
        tile[ty + j][tx] = f2bf(is_f32 ? load_f32_scrub(W, idx) : load_bf16_scrub(W, idx));
    }
    __syncthreads();
    int nx = blockIdx.y * 32 + tx;
    int ny0 = blockIdx.x * 32 + blockIdx.z * 1024;
#pragma unroll
    for (int j = 0; j < 32; j += 8) Wt[(size_t)(ny0 + ty + j) * 1024 + nx] = tile[tx][ty + j];
}

__global__ void transpose_w(const ushort_t* __restrict__ W, ushort_t* __restrict__ Wt,
                            const ushort_t* __restrict__ probe) {
    int is_f32 = probe_is_f32(probe);
    __shared__ ushort_t tile[32][33];
    int tx = threadIdx.x, ty = threadIdx.y;
    int x = blockIdx.x * 32 + tx;
    int y0 = blockIdx.y * 32;
#pragma unroll
    for (int j = 0; j < 32; j += 8) {
        size_t idx = (size_t)(y0 + ty + j) * 1024 + x;
        tile[ty + j][tx] = f2bf(is_f32 ? load_f32_scrub(W, idx) : load_bf16_scrub(W, idx));
    }
    __syncthreads();
    int nx = blockIdx.y * 32 + tx;
    int ny0 = blockIdx.x * 32;
#pragma unroll
    for (int j = 0; j < 32; j += 8) Wt[(size_t)(ny0 + ty + j) * 1024 + nx] = tile[tx][ty + j];
}

// ------------------------------------------------------------------- GEMM ---
// Round-8 structure (VERIFIED 70 µs): 128x128 block tile, BK=32, async
// staging with COALESCED lane map (4 consecutive lanes = 64 B of one row —
// do NOT "fix" the LDS bank conflicts by remapping lanes: R9 proved the
// b128 conflicts are benign while staging coalescing is the binding factor).
// + R9's XCD-region swizzle (verified FETCH 40->25 MB).
// MODE 0: QKV routing epilogue; MODE 1: fp32 C store.
template <int MODE>
__global__ __launch_bounds__(256, 4) void gemm_m97(const ushort_t* __restrict__ A,
                                                   const ushort_t* __restrict__ Bt,
                                                   ushort_t* __restrict__ qb,
                                                   ushort_t* __restrict__ kb,
                                                   ushort_t* __restrict__ vt,
                                                   float* __restrict__ C) {
    const int K = 1024;
    int tid = threadIdx.x;
    int lane = tid & 63, w = tid >> 6;
    int c = lane & 15, quad = lane >> 4;
    int mh = w >> 1, nh = w & 1;
    // XCD-region swizzle (grid.x * grid.y must be a multiple of 64)
    int lin = blockIdx.y * gridDim.x + blockIdx.x;
    int xcd = lin & 7, idx = lin >> 3;
    int XN = (gridDim.x * gridDim.y) >> 6;          // n-blocks per XCD region
    int bm = ((xcd & 3) * 8 + (idx & 7)) * 128;
    int bn = ((xcd >> 2) * XN + (idx >> 3)) * 128;
    int lr = lane >> 2, lq = lane & 3;       // staging: lane -> (row, k-chunk)

    __shared__ __align__(16) ushort_t As[8 * 512];
    __shared__ __align__(16) ushort_t Bs[8 * 512];

    const floatx4 zero = {0.f, 0.f, 0.f, 0.f};
    floatx4 acc[4][4];
#pragma unroll
    for (int i = 0; i < 4; i++)
#pragma unroll
        for (int j = 0; j < 4; j++) acc[i][j] = zero;

    for (int k0 = 0; k0 < K; k0 += 32) {
        __syncthreads();
#pragma unroll
        for (int ci = 0; ci < 4; ci++) {
            int ch = w * 4 + ci;
            if (ch < 8)
                async16(A + (size_t)(bm + ch * 16 + lr) * K + k0 + lq * 8, As + ch * 512);
            else
                async16(Bt + (size_t)(bn + (ch - 8) * 16 + lr) * K + k0 + lq * 8,
                        Bs + (ch - 8) * 512);
        }
        __syncthreads();
        short8 af[4], bf[4];
#pragma unroll
        for (int i = 0; i < 4; i++)
            af[i] = *(const short8*)(As + (mh * 4 + i) * 512 + c * 32 + quad * 8);
#pragma unroll
        for (int j = 0; j < 4; j++)
            bf[j] = *(const short8*)(Bs + (nh * 4 + j) * 512 + c * 32 + quad * 8);
#pragma unroll
        for (int i = 0; i < 4; i++)
#pragma unroll
            for (int j = 0; j < 4; j++)
                acc[i][j] = __builtin_amdgcn_mfma_f32_16x16x32_bf16(af[i], bf[j], acc[i][j], 0, 0, 0);
    }

    if (MODE == 0) {
        int proj = bn >> 10;                 // 0=q, 1=k, 2=v (blocks never straddle)
        int n0 = (bn & 1023) + nh * 64;
        if (proj < 2) {                      // RoPE: d = j*16+c, pairs (j, j+2)
            float th0 = exp2f((float)c * (-19.931568569324174f / 32.0f));
            float th1 = exp2f((float)(16 + c) * (-19.931568569324174f / 32.0f));
            float scale = (proj == 0) ? 0.125f : 1.0f;
#pragma unroll
            for (int i = 0; i < 4; i++)
#pragma unroll
                for (int r = 0; r < 4; r++) {
                    int s = (bm + mh * 64 + i * 16 + quad * 4 + r) & 2047;
                    float sn0, cs0, sn1, cs1;
                    sincosf((float)s * th0, &sn0, &cs0);
                    sincosf((float)s * th1, &sn1, &cs1);
                    float x1a = acc[i][0][r], x2a = acc[i][2][r];
                    acc[i][0][r] = (x1a * cs0 - x2a * sn0) * scale;
                    acc[i][2][r] = (x1a * sn0 + x2a * cs0) * scale;
                    float x1b = acc[i][1][r], x2b = acc[i][3][r];
                    acc[i][1][r] = (x1b * cs1 - x2b * sn1) * scale;
                    acc[i][3][r] = (x1b * sn1 + x2b * cs1) * scale;
                }
        }
        ushort_t* dst = (proj == 0) ? qb : kb;
#pragma unroll
        for (int i = 0; i < 4; i++)
#pragma unroll
            for (int j = 0; j < 4; j++)
#pragma unroll
                for (int r = 0; r < 4; r++) {
                    int row = bm + mh * 64 + i * 16 + quad * 4 + r;
                    int col = n0 + j * 16 + c;
                    if (proj == 2) {
                        int b = row >> 11, s = row & 2047;
                        int hh = col >> 6, dh = col & 63;
                        vt[(size_t)((b * 16 + hh) * 64 + dh) * 2048 + s] = f2bf(acc[i][j][r]);
                    } else {
                        dst[(size_t)row * 1024 + col] = f2bf(acc[i][j][r]);
                    }
                }
    } else {
#pragma unroll
        for (int i = 0; i < 4; i++)
#pragma unroll
            for (int j = 0; j < 4; j++)
#pragma unroll
                for (int r = 0; r < 4; r++) {
                    int row = bm + mh * 64 + i * 16 + quad * 4 + r;
                    int col = bn + nh * 64 + j * 16 + c;
                    C[(size_t)row * 1024 + col] = acc[i][j][r];
                }
    }
}

// -------------------------------------------------------------- attention ---
// Round-8 structure (verified <70 µs): grid (bh=32, pair=16) XCD-locality;
// uniform pairing (qt, 31-qt) = 33 key-tiles/block; COALESCED async staging.
__global__ __launch_bounds__(256) void attn_kernel(const ushort_t* __restrict__ q,
                                                   const ushort_t* __restrict__ k,
                                                   const ushort_t* __restrict__ vt,
                                                   ushort_t* __restrict__ o) {
    int tid = threadIdx.x;
    int lane = tid & 63, w = tid >> 6;
    int c = lane & 15, quad = lane >> 4;
    int bh = blockIdx.x;
    int b = bh >> 4, h = bh & 15;
    int pair = blockIdx.y;              // 0..15
    int lr = lane >> 2, lq = lane & 3;
    const ushort_t* qb  = q + (size_t)b * 2048 * 1024 + h * 64;
    const ushort_t* kbp = k + (size_t)b * 2048 * 1024 + h * 64;
    const ushort_t* vtb = vt + (size_t)(b * 16 + h) * 64 * 2048;
    ushort_t* ob = o + (size_t)b * 2048 * 1024 + h * 64;

    __shared__ __align__(16) ushort_t Ks[8 * 512];   // frag (nt, half): 16 keys x 32 dh
    __shared__ __align__(16) ushort_t Vs[8 * 512];   // frag (dt, half): 16 dh x 32 s
    __shared__ __align__(16) ushort_t Ps[64 * 72];

    const floatx4 zero = {0.f, 0.f, 0.f, 0.f};

#pragma unroll
    for (int g = 0; g < 2; g++) {
        int qt  = g ? (31 - pair) : pair;
        int t0b = qt * 64;
        int t0w = t0b + w * 16;
        int ntile = qt + 1;

        const ushort_t* qrow = qb + (size_t)(t0w + c) * 1024;
        short8 aq0 = *(const short8*)(qrow + quad * 8);
        short8 aq1 = *(const short8*)(qrow + 32 + quad * 8);

        float l_part[4];
        floatx4 oacc[4];
#pragma unroll
        for (int r = 0; r < 4; r++) l_part[r] = 0.f;
#pragma unroll
        for (int dt = 0; dt < 4; dt++) oacc[dt] = zero;

        for (int kt = 0; kt < ntile; kt++) {
            int s0 = kt * 64;
            __syncthreads();     // protect Ks/Vs from previous tile's readers
#pragma unroll
            for (int ci = 0; ci < 4; ci++) {
                int ch = w * 4 + ci;
                if (ch < 8) {
                    int nt = ch >> 1, hf = ch & 1;
                    async16(kbp + (size_t)(s0 + nt * 16 + lr) * 1024 + hf * 32 + lq * 8,
                            Ks + ch * 512);
                } else {
                    int dt = (ch - 8) >> 1, hf = ch & 1;
                    async16(vtb + (size_t)(dt * 16 + lr) * 2048 + s0 + hf * 32 + lq * 8,
                            Vs + (ch - 8) * 512);
                }
            }
            __syncthreads();

            floatx4 sacc[4];
#pragma unroll
            for (int nt = 0; nt < 4; nt++) sacc[nt] = zero;
#pragma unroll
            for (int nt = 0; nt < 4; nt++) {
                short8 b0 = *(const short8*)(Ks + nt * 1024 + c * 32 + quad * 8);
                short8 b1 = *(const short8*)(Ks + nt * 1024 + 512 + c * 32 + quad * 8);
                sacc[nt] = __builtin_amdgcn_mfma_f32_16x16x32_bf16(aq0, b0, sacc[nt], 0, 0, 0);
                sacc[nt] = __builtin_amdgcn_mfma_f32_16x16x32_bf16(aq1, b1, sacc[nt], 0, 0, 0);
            }

            if (kt == ntile - 1) {   // diagonal tile: causal mask
#pragma unroll
                for (int r = 0; r < 4; r++) {
                    int t = t0w + quad * 4 + r;
                    float ps = 0.f;
#pragma unroll
                    for (int nt = 0; nt < 4; nt++) {
                        float v = (s0 + nt * 16 + c > t) ? NEG_BIG : sacc[nt][r];
                        float e = __expf(v);
                        ps += e;
                        Ps[(w * 16 + quad * 4 + r) * 72 + nt * 16 + c] = f2bf(e);
                    }
                    l_part[r] += ps;
                }
            } else {
#pragma unroll
                for (int r = 0; r < 4; r++) {
                    float ps = 0.f;
#pragma unroll
                    for (int nt = 0; nt < 4; nt++) {
                        float e = __expf(sacc[nt][r]);
                        ps += e;
                        Ps[(w * 16 + quad * 4 + r) * 72 + nt * 16 + c] = f2bf(e);
                    }
                    l_part[r] += ps;
                }
            }

            short8 pa0 = *(const short8*)(Ps + (w * 16 + c) * 72 + quad * 8);
            short8 pa1 = *(const short8*)(Ps + (w * 16 + c) * 72 + 32 + quad * 8);
#pragma unroll
            for (int dt = 0; dt < 4; dt++) {
                short8 v0 = *(const short8*)(Vs + dt * 1024 + c * 32 + quad * 8);
                short8 v1 = *(const short8*)(Vs + dt * 1024 + 512 + c * 32 + quad * 8);
                oacc[dt] = __builtin_amdgcn_mfma_f32_16x16x32_bf16(pa0, v0, oacc[dt], 0, 0, 0);
                oacc[dt] = __builtin_amdgcn_mfma_f32_16x16x32_bf16(pa1, v1, oacc[dt], 0, 0, 0);
            }
        }

        float linv[4];
#pragma unroll
        for (int r = 0; r < 4; r++) {
            float l = l_part[r];
#pragma unroll
            for (int off = 1; off < 16; off <<= 1) l += __shfl_xor(l, off);
            linv[r] = 1.0f / l;
        }
#pragma unroll
        for (int dt = 0; dt < 4; dt++)
#pragma unroll
            for (int r = 0; r < 4; r++) {
                int t = t0w + quad * 4 + r;
                ob[(size_t)t * 1024 + dt * 16 + c] = f2bf(oacc[dt][r] * linv[r]);
            }
    }
}

// ------------------------------------------------------------------ launch ---
extern "C" void kernel_launch(void* const* d_in, const int* in_sizes, int n_in,
                              void* d_out, int out_size, void* d_ws, size_t ws_size,
                              hipStream_t stream) {
    const ushort_t* x  = (const ushort_t*)d_in[0];
    const ushort_t* g  = (const ushort_t*)d_in[1];
    const ushort_t* Wq = (const ushort_t*)d_in[2];
    const ushort_t* Wk = (const ushort_t*)d_in[3];
    const ushort_t* Wv = (const ushort_t*)d_in[4];
    const ushort_t* Wo = (const ushort_t*)d_in[5];

    char* ws = (char*)d_ws;
    const size_t MB = 1ull << 20;
    ushort_t* xn   = (ushort_t*)(ws);            // 8 MB (reused as attn out)
    ushort_t* qb   = (ushort_t*)(ws + 8 * MB);   // 8 MB
    ushort_t* kb   = (ushort_t*)(ws + 16 * MB);  // 8 MB
    ushort_t* vt   = (ushort_t*)(ws + 24 * MB);  // 8 MB ([b,h,dh,s])
    ushort_t* WTq3 = (ushort_t*)(ws + 32 * MB);  // 6 MB (q|k|v transposed)
    ushort_t* WoT  = (ushort_t*)(ws + 38 * MB);  // 2 MB  -> total 40 MB
    ushort_t* at   = xn;

    dim3 tb(32, 8);
    rmsnorm_kernel<<<4096, 256, 0, stream>>>(x, g, xn);
    transpose_qkv<<<dim3(32, 32, 3), tb, 0, stream>>>(Wq, Wk, Wv, WTq3, x);
    transpose_w<<<dim3(32, 32), tb, 0, stream>>>(Wo, WoT, x);

    gemm_m97<0><<<dim3(24, 32), 256, 0, stream>>>(xn, WTq3, qb, kb, vt, nullptr);

    attn_kernel<<<dim3(32, 16), 256, 0, stream>>>(qb, kb, vt, at);

    gemm_m97<1><<<dim3(8, 32), 256, 0, stream>>>(at, WoT, nullptr, nullptr, nullptr, (float*)d_out);
}

// Round 11
// 212.532 us; speedup vs baseline: 1.3774x; 1.0679x over previous
//
#include <hip/hip_runtime.h>

typedef unsigned short ushort_t;
typedef __attribute__((ext_vector_type(8))) short short8;   // 8 bf16 (4 VGPRs)
typedef __attribute__((ext_vector_type(4))) float floatx4;  // 4 fp32 acc

#define DEV static __device__ __forceinline__
#define NEG_BIG (-1e30f)

typedef const __attribute__((address_space(1))) unsigned int* gas_ptr;
typedef __attribute__((address_space(3))) unsigned int* las_ptr;

// async global->LDS, 16B per lane; LDS dest = base + lane*16 (wave-uniform base)
DEV void async16(const ushort_t* g, ushort_t* l) {
    __builtin_amdgcn_global_load_lds((gas_ptr)(const void*)g, (las_ptr)(void*)l, 16, 0, 0);
}

DEV float bf2f(ushort_t u) {
    union { unsigned u; float f; } v; v.u = ((unsigned)u) << 16; return v.f;
}
DEV ushort_t f2bf(float f) {
    union { float f; unsigned u; } v; v.f = f;
    unsigned r = v.u + 0x7FFF + ((v.u >> 16) & 1);   // RNE
    return (ushort_t)(r >> 16);
}
DEV float load_bf16_scrub(const ushort_t* p, size_t i) {
    ushort_t u = p[i];
    if (((u >> 7) & 0xFF) == 0xFF) u = 0;
    return bf2f(u);
}
DEV float load_f32_scrub(const ushort_t* p, size_t i) {
    unsigned u = ((const unsigned*)p)[i];
    if (((u >> 23) & 0xFF) == 0xFF) u = 0;
    union { unsigned u; float f; } v; v.u = u; return v.f;
}

// Probe: fp32 vs bf16 raw data (proven in R3/R4). Block-uniform result.
DEV int probe_is_f32(const ushort_t* __restrict__ p) {
    int tid = threadIdx.x + threadIdx.y * blockDim.x;
    int nthr = blockDim.x * blockDim.y;
    __shared__ int cnt;
    if (tid == 0) cnt = 0;
    __syncthreads();
    int weird = 0;
    for (int i = tid; i < 2048; i += nthr) {
        unsigned e = (p[i] >> 7) & 0xFF;
        weird += (e >= 0x90) ? 1 : 0;
    }
#pragma unroll
    for (int off = 32; off; off >>= 1) weird += __shfl_xor(weird, off);
    if ((tid & 63) == 0) atomicAdd(&cnt, weird);
    __syncthreads();
    return cnt > 16;
}

// ----------------------------------------------- fused prep (1 launch) ------
// grid (32,32,8), threads (32,8).
// z=0..2: transpose Wq/Wk/Wv -> WTq3 (+z*1024 row offset). z=3: Wo -> WoT.
// z=4..7: RMSNorm rows (z-4)*1024 + by*32 + bx.
__global__ void prep_kernel(const ushort_t* __restrict__ W0,
                            const ushort_t* __restrict__ W1,
                            const ushort_t* __restrict__ W2,
                            const ushort_t* __restrict__ W3,
                            ushort_t* __restrict__ WTq3,
                            ushort_t* __restrict__ WoT,
                            const ushort_t* __restrict__ x,
                            const ushort_t* __restrict__ g,
                            ushort_t* __restrict__ xn) {
    int is_f32 = probe_is_f32(x);
    int z = blockIdx.z;
    if (z < 4) {
        const ushort_t* W = (z == 0) ? W0 : (z == 1) ? W1 : (z == 2) ? W2 : W3;
        __shared__ ushort_t tile[32][33];
        int tx = threadIdx.x, ty = threadIdx.y;
        int xx = blockIdx.x * 32 + tx;      // n
        int y0 = blockIdx.y * 32;           // k
#pragma unroll
        for (int j = 0; j < 32; j += 8) {
            size_t idx = (size_t)(y0 + ty + j) * 1024 + xx;
            tile[ty + j][tx] = f2bf(is_f32 ? load_f32_scrub(W, idx) : load_bf16_scrub(W, idx));
        }
        __syncthreads();
        int nx = blockIdx.y * 32 + tx;
        ushort_t* dst = (z < 3) ? WTq3 : WoT;
        int ny0 = blockIdx.x * 32 + ((z < 3) ? z * 1024 : 0);
#pragma unroll
        for (int j = 0; j < 32; j += 8)
            dst[(size_t)(ny0 + ty + j) * 1024 + nx] = tile[tx][ty + j];
    } else {
        int row = (z - 4) * 1024 + blockIdx.y * 32 + blockIdx.x;
        int tid = threadIdx.y * 32 + threadIdx.x;
        float vals[4], gv[4];
        size_t base = (size_t)row * 1024 + tid * 4;
#pragma unroll
        for (int i = 0; i < 4; i++) {
            if (is_f32) {
                vals[i] = load_f32_scrub(x, base + i);
                gv[i]   = load_f32_scrub(g, tid * 4 + i);
            } else {
                vals[i] = load_bf16_scrub(x, base + i);
                gv[i]   = load_bf16_scrub(g, tid * 4 + i);
            }
        }
        float ss = vals[0]*vals[0] + vals[1]*vals[1] + vals[2]*vals[2] + vals[3]*vals[3];
#pragma unroll
        for (int off = 32; off > 0; off >>= 1) ss += __shfl_xor(ss, off);
        __shared__ float red[4];
        if ((tid & 63) == 0) red[tid >> 6] = ss;
        __syncthreads();
        ss = red[0] + red[1] + red[2] + red[3];
        float inv = rsqrtf(ss * (1.0f / 1024.0f) + 1e-6f);
#pragma unroll
        for (int i = 0; i < 4; i++)
            xn[base + i] = f2bf(vals[i] * inv * gv[i]);
    }
}

// ------------------------------------------------------- fused QKV GEMM ----
// 128x128 block tile, BK=64 (16 k-steps — half the barrier drains of R10),
// COALESCED async staging (R8/R10-verified lane map: 4 consecutive lanes =
// 64 B of one row; do NOT remap for LDS bank conflicts — R9 proved those
// benign while staging coalescing is binding). XCD-region swizzle (R9/R10-
// verified FETCH reduction). Epilogue routes q(+RoPE,x1/8) / k(+RoPE) / v(scatter).
__global__ __launch_bounds__(256, 4) void gemm_qkv(const ushort_t* __restrict__ A,
                                                   const ushort_t* __restrict__ Bt,
                                                   ushort_t* __restrict__ qb,
                                                   ushort_t* __restrict__ kb,
                                                   ushort_t* __restrict__ vt) {
    const int K = 1024;
    int tid = threadIdx.x;
    int lane = tid & 63, w = tid >> 6;
    int c = lane & 15, quad = lane >> 4;
    int mh = w >> 1, nh = w & 1;
    int lin = blockIdx.y * gridDim.x + blockIdx.x;     // 768 blocks
    int xcd = lin & 7, idx = lin >> 3;
    int bm = ((xcd & 3) * 8 + (idx & 7)) * 128;        // m-block in [0,32)
    int bn = ((xcd >> 2) * 12 + (idx >> 3)) * 128;     // n-block in [0,24)
    int lr = lane >> 2, lq = lane & 3;                 // staging lane -> (row, 8-short chunk)

    __shared__ __align__(16) ushort_t As[16 * 512];    // 16 KB
    __shared__ __align__(16) ushort_t Bs[16 * 512];    // 16 KB

    const floatx4 zero = {0.f, 0.f, 0.f, 0.f};
    floatx4 acc[4][4];
#pragma unroll
    for (int i = 0; i < 4; i++)
#pragma unroll
        for (int j = 0; j < 4; j++) acc[i][j] = zero;

    for (int k0 = 0; k0 < K; k0 += 64) {
        __syncthreads();
#pragma unroll
        for (int ci = 0; ci < 8; ci++) {
            int ch = w * 8 + ci;              // 0..31, wave-uniform
            if (ch < 16) {
                int rg = ch >> 1, kc = ch & 1;
                async16(A + (size_t)(bm + rg * 16 + lr) * K + k0 + kc * 32 + lq * 8,
                        As + ch * 512);
            } else {
                int b2 = ch - 16;
                int rg = b2 >> 1, kc = b2 & 1;
                async16(Bt + (size_t)(bn + rg * 16 + lr) * K + k0 + kc * 32 + lq * 8,
                        Bs + b2 * 512);
            }
        }
        __syncthreads();
#pragma unroll
        for (int kc = 0; kc < 2; kc++) {
            short8 af[4], bf[4];
#pragma unroll
            for (int i = 0; i < 4; i++)
                af[i] = *(const short8*)(As + ((mh * 4 + i) * 2 + kc) * 512 + c * 32 + quad * 8);
#pragma unroll
            for (int j = 0; j < 4; j++)
                bf[j] = *(const short8*)(Bs + ((nh * 4 + j) * 2 + kc) * 512 + c * 32 + quad * 8);
#pragma unroll
            for (int i = 0; i < 4; i++)
#pragma unroll
                for (int j = 0; j < 4; j++)
                    acc[i][j] = __builtin_amdgcn_mfma_f32_16x16x32_bf16(af[i], bf[j], acc[i][j], 0, 0, 0);
        }
    }

    int proj = bn >> 10;                 // 0=q, 1=k, 2=v (blocks never straddle)
    int n0 = (bn & 1023) + nh * 64;
    if (proj < 2) {                      // RoPE: d = j*16+c, pairs (j, j+2)
        float th0 = exp2f((float)c * (-19.931568569324174f / 32.0f));
        float th1 = exp2f((float)(16 + c) * (-19.931568569324174f / 32.0f));
        float scale = (proj == 0) ? 0.125f : 1.0f;
#pragma unroll
        for (int i = 0; i < 4; i++)
#pragma unroll
            for (int r = 0; r < 4; r++) {
                int s = (bm + mh * 64 + i * 16 + quad * 4 + r) & 2047;
                float sn0, cs0, sn1, cs1;
                sincosf((float)s * th0, &sn0, &cs0);
                sincosf((float)s * th1, &sn1, &cs1);
                float x1a = acc[i][0][r], x2a = acc[i][2][r];
                acc[i][0][r] = (x1a * cs0 - x2a * sn0) * scale;
                acc[i][2][r] = (x1a * sn0 + x2a * cs0) * scale;
                float x1b = acc[i][1][r], x2b = acc[i][3][r];
                acc[i][1][r] = (x1b * cs1 - x2b * sn1) * scale;
                acc[i][3][r] = (x1b * sn1 + x2b * cs1) * scale;
            }
    }
    ushort_t* dst = (proj == 0) ? qb : kb;
#pragma unroll
    for (int i = 0; i < 4; i++)
#pragma unroll
        for (int j = 0; j < 4; j++)
#pragma unroll
            for (int r = 0; r < 4; r++) {
                int row = bm + mh * 64 + i * 16 + quad * 4 + r;
                int col = n0 + j * 16 + c;
                if (proj == 2) {
                    int b = row >> 11, s = row & 2047;
                    int hh = col >> 6, dh = col & 63;
                    vt[(size_t)((b * 16 + hh) * 64 + dh) * 2048 + s] = f2bf(acc[i][j][r]);
                } else {
                    dst[(size_t)row * 1024 + col] = f2bf(acc[i][j][r]);
                }
            }
}

// ----------------------------------------------------- output projection ---
// 128m x 64n block tile (512 blocks = 2/CU — R10's 256-block 1/CU grid was
// occupancy-starved), BK=64, coalesced staging, fp32 out. Wave tile 64x32.
__global__ __launch_bounds__(256, 4) void gemm_out(const ushort_t* __restrict__ A,
                                                   const ushort_t* __restrict__ Bt,
                                                   float* __restrict__ C) {
    const int K = 1024, N = 1024;
    int tid = threadIdx.x;
    int lane = tid & 63, w = tid >> 6;
    int c = lane & 15, quad = lane >> 4;
    int mh = w >> 1, nh = w & 1;
    int lin = blockIdx.y * gridDim.x + blockIdx.x;     // 512 blocks
    int xcd = lin & 7, idx = lin >> 3;
    int bm = ((xcd & 3) * 8 + (idx & 7)) * 128;        // m-block in [0,32)
    int bn = ((xcd >> 2) * 8 + (idx >> 3)) * 64;       // n-block in [0,16)
    int lr = lane >> 2, lq = lane & 3;

    __shared__ __align__(16) ushort_t As[16 * 512];    // 16 KB
    __shared__ __align__(16) ushort_t Bs[8 * 512];     // 8 KB

    const floatx4 zero = {0.f, 0.f, 0.f, 0.f};
    floatx4 acc[4][2];
#pragma unroll
    for (int i = 0; i < 4; i++)
#pragma unroll
        for (int j = 0; j < 2; j++) acc[i][j] = zero;

    for (int k0 = 0; k0 < K; k0 += 64) {
        __syncthreads();
#pragma unroll
        for (int ci = 0; ci < 6; ci++) {
            int ch = w * 6 + ci;              // 0..23, wave-uniform
            if (ch < 16) {
                int rg = ch >> 1, kc = ch & 1;
                async16(A + (size_t)(bm + rg * 16 + lr) * K + k0 + kc * 32 + lq * 8,
                        As + ch * 512);
            } else {
                int b2 = ch - 16;
                int rg = b2 >> 1, kc = b2 & 1;
                async16(Bt + (size_t)(bn + rg * 16 + lr) * K + k0 + kc * 32 + lq * 8,
                        Bs + b2 * 512);
            }
        }
        __syncthreads();
#pragma unroll
        for (int kc = 0; kc < 2; kc++) {
            short8 af[4], bf[2];
#pragma unroll
            for (int i = 0; i < 4; i++)
                af[i] = *(const short8*)(As + ((mh * 4 + i) * 2 + kc) * 512 + c * 32 + quad * 8);
#pragma unroll
            for (int j = 0; j < 2; j++)
                bf[j] = *(const short8*)(Bs + ((nh * 2 + j) * 2 + kc) * 512 + c * 32 + quad * 8);
#pragma unroll
            for (int i = 0; i < 4; i++)
#pragma unroll
                for (int j = 0; j < 2; j++)
                    acc[i][j] = __builtin_amdgcn_mfma_f32_16x16x32_bf16(af[i], bf[j], acc[i][j], 0, 0, 0);
        }
    }
#pragma unroll
    for (int i = 0; i < 4; i++)
#pragma unroll
        for (int j = 0; j < 2; j++)
#pragma unroll
            for (int r = 0; r < 4; r++) {
                int row = bm + mh * 64 + i * 16 + quad * 4 + r;
                int col = bn + nh * 32 + j * 16 + c;
                C[(size_t)row * N + col] = acc[i][j][r];
            }
}

// -------------------------------------------------------------- attention ---
// R10-verified: grid (bh=32, pair=16) XCD-locality; uniform pairing
// (qt, 31-qt) = 33 key-tiles/block; coalesced async staging; no online max.
__global__ __launch_bounds__(256) void attn_kernel(const ushort_t* __restrict__ q,
                                                   const ushort_t* __restrict__ k,
                                                   const ushort_t* __restrict__ vt,
                                                   ushort_t* __restrict__ o) {
    int tid = threadIdx.x;
    int lane = tid & 63, w = tid >> 6;
    int c = lane & 15, quad = lane >> 4;
    int bh = blockIdx.x;
    int b = bh >> 4, h = bh & 15;
    int pair = blockIdx.y;              // 0..15
    int lr = lane >> 2, lq = lane & 3;
    const ushort_t* qb  = q + (size_t)b * 2048 * 1024 + h * 64;
    const ushort_t* kbp = k + (size_t)b * 2048 * 1024 + h * 64;
    const ushort_t* vtb = vt + (size_t)(b * 16 + h) * 64 * 2048;
    ushort_t* ob = o + (size_t)b * 2048 * 1024 + h * 64;

    __shared__ __align__(16) ushort_t Ks[8 * 512];
    __shared__ __align__(16) ushort_t Vs[8 * 512];
    __shared__ __align__(16) ushort_t Ps[64 * 72];

    const floatx4 zero = {0.f, 0.f, 0.f, 0.f};

#pragma unroll
    for (int g = 0; g < 2; g++) {
        int qt  = g ? (31 - pair) : pair;
        int t0b = qt * 64;
        int t0w = t0b + w * 16;
        int ntile = qt + 1;

        const ushort_t* qrow = qb + (size_t)(t0w + c) * 1024;
        short8 aq0 = *(const short8*)(qrow + quad * 8);
        short8 aq1 = *(const short8*)(qrow + 32 + quad * 8);

        float l_part[4];
        floatx4 oacc[4];
#pragma unroll
        for (int r = 0; r < 4; r++) l_part[r] = 0.f;
#pragma unroll
        for (int dt = 0; dt < 4; dt++) oacc[dt] = zero;

        for (int kt = 0; kt < ntile; kt++) {
            int s0 = kt * 64;
            __syncthreads();
#pragma unroll
            for (int ci = 0; ci < 4; ci++) {
                int ch = w * 4 + ci;
                if (ch < 8) {
                    int nt = ch >> 1, hf = ch & 1;
                    async16(kbp + (size_t)(s0 + nt * 16 + lr) * 1024 + hf * 32 + lq * 8,
                            Ks + ch * 512);
                } else {
                    int dt = (ch - 8) >> 1, hf = ch & 1;
                    async16(vtb + (size_t)(dt * 16 + lr) * 2048 + s0 + hf * 32 + lq * 8,
                            Vs + (ch - 8) * 512);
                }
            }
            __syncthreads();

            floatx4 sacc[4];
#pragma unroll
            for (int nt = 0; nt < 4; nt++) sacc[nt] = zero;
#pragma unroll
            for (int nt = 0; nt < 4; nt++) {
                short8 b0 = *(const short8*)(Ks + nt * 1024 + c * 32 + quad * 8);
                short8 b1 = *(const short8*)(Ks + nt * 1024 + 512 + c * 32 + quad * 8);
                sacc[nt] = __builtin_amdgcn_mfma_f32_16x16x32_bf16(aq0, b0, sacc[nt], 0, 0, 0);
                sacc[nt] = __builtin_amdgcn_mfma_f32_16x16x32_bf16(aq1, b1, sacc[nt], 0, 0, 0);
            }

            if (kt == ntile - 1) {   // diagonal tile: causal mask
#pragma unroll
                for (int r = 0; r < 4; r++) {
                    int t = t0w + quad * 4 + r;
                    float ps = 0.f;
#pragma unroll
                    for (int nt = 0; nt < 4; nt++) {
                        float v = (s0 + nt * 16 + c > t) ? NEG_BIG : sacc[nt][r];
                        float e = __expf(v);
                        ps += e;
                        Ps[(w * 16 + quad * 4 + r) * 72 + nt * 16 + c] = f2bf(e);
                    }
                    l_part[r] += ps;
                }
            } else {
#pragma unroll
                for (int r = 0; r < 4; r++) {
                    float ps = 0.f;
#pragma unroll
                    for (int nt = 0; nt < 4; nt++) {
                        float e = __expf(sacc[nt][r]);
                        ps += e;
                        Ps[(w * 16 + quad * 4 + r) * 72 + nt * 16 + c] = f2bf(e);
                    }
                    l_part[r] += ps;
                }
            }

            short8 pa0 = *(const short8*)(Ps + (w * 16 + c) * 72 + quad * 8);
            short8 pa1 = *(const short8*)(Ps + (w * 16 + c) * 72 + 32 + quad * 8);
#pragma unroll
            for (int dt = 0; dt < 4; dt++) {
                short8 v0 = *(const short8*)(Vs + dt * 1024 + c * 32 + quad * 8);
                short8 v1 = *(const short8*)(Vs + dt * 1024 + 512 + c * 32 + quad * 8);
                oacc[dt] = __builtin_amdgcn_mfma_f32_16x16x32_bf16(pa0, v0, oacc[dt], 0, 0, 0);
                oacc[dt] = __builtin_amdgcn_mfma_f32_16x16x32_bf16(pa1, v1, oacc[dt], 0, 0, 0);
            }
        }

        float linv[4];
#pragma unroll
        for (int r = 0; r < 4; r++) {
            float l = l_part[r];
#pragma unroll
            for (int off = 1; off < 16; off <<= 1) l += __shfl_xor(l, off);
            linv[r] = 1.0f / l;
        }
#pragma unroll
        for (int dt = 0; dt < 4; dt++)
#pragma unroll
            for (int r = 0; r < 4; r++) {
                int t = t0w + quad * 4 + r;
                ob[(size_t)t * 1024 + dt * 16 + c] = f2bf(oacc[dt][r] * linv[r]);
            }
    }
}

// ------------------------------------------------------------------ launch ---
extern "C" void kernel_launch(void* const* d_in, const int* in_sizes, int n_in,
                              void* d_out, int out_size, void* d_ws, size_t ws_size,
                              hipStream_t stream) {
    const ushort_t* x  = (const ushort_t*)d_in[0];
    const ushort_t* g  = (const ushort_t*)d_in[1];
    const ushort_t* Wq = (const ushort_t*)d_in[2];
    const ushort_t* Wk = (const ushort_t*)d_in[3];
    const ushort_t* Wv = (const ushort_t*)d_in[4];
    const ushort_t* Wo = (const ushort_t*)d_in[5];

    char* ws = (char*)d_ws;
    const size_t MB = 1ull << 20;
    ushort_t* xn   = (ushort_t*)(ws);            // 8 MB (reused as attn out)
    ushort_t* qb   = (ushort_t*)(ws + 8 * MB);   // 8 MB
    ushort_t* kb   = (ushort_t*)(ws + 16 * MB);  // 8 MB
    ushort_t* vt   = (ushort_t*)(ws + 24 * MB);  // 8 MB ([b,h,dh,s])
    ushort_t* WTq3 = (ushort_t*)(ws + 32 * MB);  // 6 MB (q|k|v transposed)
    ushort_t* WoT  = (ushort_t*)(ws + 38 * MB);  // 2 MB  -> total 40 MB
    ushort_t* at   = xn;

    prep_kernel<<<dim3(32, 32, 8), dim3(32, 8), 0, stream>>>(Wq, Wk, Wv, Wo, WTq3, WoT, x, g, xn);

    gemm_qkv<<<dim3(24, 32), 256, 0, stream>>>(xn, WTq3, qb, kb, vt);

    attn_kernel<<<dim3(32, 16), 256, 0, stream>>>(qb, kb, vt, at);

    gemm_out<<<dim3(16, 32), 256, 0, stream>>>(at, WoT, (float*)d_out);
}

// Round 12
// 187.270 us; speedup vs baseline: 1.5632x; 1.1349x over previous
//
#include <hip/hip_runtime.h>

typedef unsigned short ushort_t;
typedef __attribute__((ext_vector_type(8))) short short8;   // 8 bf16 (4 VGPRs)
typedef __attribute__((ext_vector_type(4))) short short4v;  // 4 bf16 (8 B)
typedef __attribute__((ext_vector_type(4))) float floatx4;  // 4 fp32 acc

#define DEV static __device__ __forceinline__
#define NEG_BIG (-1e30f)

typedef const __attribute__((address_space(1))) unsigned int* gas_ptr;
typedef __attribute__((address_space(3))) unsigned int* las_ptr;

// async global->LDS, 16B per lane; LDS dest = base + lane*16 (wave-uniform base)
DEV void async16(const ushort_t* g, ushort_t* l) {
    __builtin_amdgcn_global_load_lds((gas_ptr)(const void*)g, (las_ptr)(void*)l, 16, 0, 0);
}

DEV float bf2f(ushort_t u) {
    union { unsigned u; float f; } v; v.u = ((unsigned)u) << 16; return v.f;
}
DEV ushort_t f2bf(float f) {
    union { float f; unsigned u; } v; v.f = f;
    unsigned r = v.u + 0x7FFF + ((v.u >> 16) & 1);   // RNE
    return (ushort_t)(r >> 16);
}
DEV float load_bf16_scrub(const ushort_t* p, size_t i) {
    ushort_t u = p[i];
    if (((u >> 7) & 0xFF) == 0xFF) u = 0;
    return bf2f(u);
}
DEV float load_f32_scrub(const ushort_t* p, size_t i) {
    unsigned u = ((const unsigned*)p)[i];
    if (((u >> 23) & 0xFF) == 0xFF) u = 0;
    union { unsigned u; float f; } v; v.u = u; return v.f;
}

// Probe: fp32 vs bf16 raw data (proven in R3/R4). Block-uniform result.
DEV int probe_is_f32(const ushort_t* __restrict__ p) {
    int tid = threadIdx.x + threadIdx.y * blockDim.x;
    int nthr = blockDim.x * blockDim.y;
    __shared__ int cnt;
    if (tid == 0) cnt = 0;
    __syncthreads();
    int weird = 0;
    for (int i = tid; i < 2048; i += nthr) {
        unsigned e = (p[i] >> 7) & 0xFF;
        weird += (e >= 0x90) ? 1 : 0;
    }
#pragma unroll
    for (int off = 32; off; off >>= 1) weird += __shfl_xor(weird, off);
    if ((tid & 63) == 0) atomicAdd(&cnt, weird);
    __syncthreads();
    return cnt > 16;
}

// ----------------------------------------------- fused prep (1 launch) ------
__global__ void prep_kernel(const ushort_t* __restrict__ W0,
                            const ushort_t* __restrict__ W1,
                            const ushort_t* __restrict__ W2,
                            const ushort_t* __restrict__ W3,
                            ushort_t* __restrict__ WTq3,
                            ushort_t* __restrict__ WoT,
                            const ushort_t* __restrict__ x,
                            const ushort_t* __restrict__ g,
                            ushort_t* __restrict__ xn) {
    int is_f32 = probe_is_f32(x);
    int z = blockIdx.z;
    if (z < 4) {
        const ushort_t* W = (z == 0) ? W0 : (z == 1) ? W1 : (z == 2) ? W2 : W3;
        __shared__ ushort_t tile[32][33];
        int tx = threadIdx.x, ty = threadIdx.y;
        int xx = blockIdx.x * 32 + tx;      // n
        int y0 = blockIdx.y * 32;           // k
#pragma unroll
        for (int j = 0; j < 32; j += 8) {
            size_t idx = (size_t)(y0 + ty + j) * 1024 + xx;
            tile[ty + j][tx] = f2bf(is_f32 ? load_f32_scrub(W, idx) : load_bf16_scrub(W, idx));
        }
        __syncthreads();
        int nx = blockIdx.y * 32 + tx;
        ushort_t* dst = (z < 3) ? WTq3 : WoT;
        int ny0 = blockIdx.x * 32 + ((z < 3) ? z * 1024 : 0);
#pragma unroll
        for (int j = 0; j < 32; j += 8)
            dst[(size_t)(ny0 + ty + j) * 1024 + nx] = tile[tx][ty + j];
    } else {
        int row = (z - 4) * 1024 + blockIdx.y * 32 + blockIdx.x;
        int tid = threadIdx.y * 32 + threadIdx.x;
        float vals[4], gv[4];
        size_t base = (size_t)row * 1024 + tid * 4;
#pragma unroll
        for (int i = 0; i < 4; i++) {
            if (is_f32) {
                vals[i] = load_f32_scrub(x, base + i);
                gv[i]   = load_f32_scrub(g, tid * 4 + i);
            } else {
                vals[i] = load_bf16_scrub(x, base + i);
                gv[i]   = load_bf16_scrub(g, tid * 4 + i);
            }
        }
        float ss = vals[0]*vals[0] + vals[1]*vals[1] + vals[2]*vals[2] + vals[3]*vals[3];
#pragma unroll
        for (int off = 32; off > 0; off >>= 1) ss += __shfl_xor(ss, off);
        __shared__ float red[4];
        if ((tid & 63) == 0) red[tid >> 6] = ss;
        __syncthreads();
        ss = red[0] + red[1] + red[2] + red[3];
        float inv = rsqrtf(ss * (1.0f / 1024.0f) + 1e-6f);
#pragma unroll
        for (int i = 0; i < 4; i++)
            xn[base + i] = f2bf(vals[i] * inv * gv[i]);
    }
}

// ------------------------------------------------------- fused QKV GEMM ----
// 128x128 tile, BK=64, COALESCED async staging (R8/R10-verified; R9 proved
// bank conflicts benign / coalescing binding). XCD-region swizzle.
// Epilogue: fast-math RoPE (__sinf/__cosf — hw v_sin, err ~1e-4 << bf16 ulp),
// q pre-scaled 1/8, V scattered as packed 8-B stores (4 consecutive s).
__global__ __launch_bounds__(256, 4) void gemm_qkv(const ushort_t* __restrict__ A,
                                                   const ushort_t* __restrict__ Bt,
                                                   ushort_t* __restrict__ qb,
                                                   ushort_t* __restrict__ kb,
                                                   ushort_t* __restrict__ vt) {
    const int K = 1024;
    int tid = threadIdx.x;
    int lane = tid & 63, w = tid >> 6;
    int c = lane & 15, quad = lane >> 4;
    int mh = w >> 1, nh = w & 1;
    int lin = blockIdx.y * gridDim.x + blockIdx.x;     // 768 blocks
    int xcd = lin & 7, idx = lin >> 3;
    int bm = ((xcd & 3) * 8 + (idx & 7)) * 128;        // m-block in [0,32)
    int bn = ((xcd >> 2) * 12 + (idx >> 3)) * 128;     // n-block in [0,24)
    int lr = lane >> 2, lq = lane & 3;                 // staging lane map

    __shared__ __align__(16) ushort_t As[16 * 512];    // 16 KB
    __shared__ __align__(16) ushort_t Bs[16 * 512];    // 16 KB

    const floatx4 zero = {0.f, 0.f, 0.f, 0.f};
    floatx4 acc[4][4];
#pragma unroll
    for (int i = 0; i < 4; i++)
#pragma unroll
        for (int j = 0; j < 4; j++) acc[i][j] = zero;

    for (int k0 = 0; k0 < K; k0 += 64) {
        __syncthreads();
#pragma unroll
        for (int ci = 0; ci < 8; ci++) {
            int ch = w * 8 + ci;              // 0..31, wave-uniform
            if (ch < 16) {
                int rg = ch >> 1, kc = ch & 1;
                async16(A + (size_t)(bm + rg * 16 + lr) * K + k0 + kc * 32 + lq * 8,
                        As + ch * 512);
            } else {
                int b2 = ch - 16;
                int rg = b2 >> 1, kc = b2 & 1;
                async16(Bt + (size_t)(bn + rg * 16 + lr) * K + k0 + kc * 32 + lq * 8,
                        Bs + b2 * 512);
            }
        }
        __syncthreads();
#pragma unroll
        for (int kc = 0; kc < 2; kc++) {
            short8 af[4], bf[4];
#pragma unroll
            for (int i = 0; i < 4; i++)
                af[i] = *(const short8*)(As + ((mh * 4 + i) * 2 + kc) * 512 + c * 32 + quad * 8);
#pragma unroll
            for (int j = 0; j < 4; j++)
                bf[j] = *(const short8*)(Bs + ((nh * 4 + j) * 2 + kc) * 512 + c * 32 + quad * 8);
#pragma unroll
            for (int i = 0; i < 4; i++)
#pragma unroll
                for (int j = 0; j < 4; j++)
                    acc[i][j] = __builtin_amdgcn_mfma_f32_16x16x32_bf16(af[i], bf[j], acc[i][j], 0, 0, 0);
        }
    }

    int proj = bn >> 10;                 // 0=q, 1=k, 2=v (blocks never straddle)
    int n0 = (bn & 1023) + nh * 64;
    if (proj < 2) {                      // RoPE: d = j*16+c, pairs (j, j+2)
        float th0 = exp2f((float)c * (-19.931568569324174f / 32.0f));
        float th1 = exp2f((float)(16 + c) * (-19.931568569324174f / 32.0f));
        float scale = (proj == 0) ? 0.125f : 1.0f;
#pragma unroll
        for (int i = 0; i < 4; i++)
#pragma unroll
            for (int r = 0; r < 4; r++) {
                int s = (bm + mh * 64 + i * 16 + quad * 4 + r) & 2047;
                float a0 = (float)s * th0, a1 = (float)s * th1;
                float sn0 = __sinf(a0), cs0 = __cosf(a0);
                float sn1 = __sinf(a1), cs1 = __cosf(a1);
                float x1a = acc[i][0][r], x2a = acc[i][2][r];
                acc[i][0][r] = (x1a * cs0 - x2a * sn0) * scale;
                acc[i][2][r] = (x1a * sn0 + x2a * cs0) * scale;
                float x1b = acc[i][1][r], x2b = acc[i][3][r];
                acc[i][1][r] = (x1b * cs1 - x2b * sn1) * scale;
                acc[i][3][r] = (x1b * sn1 + x2b * cs1) * scale;
            }
        ushort_t* dst = (proj == 0) ? qb : kb;
#pragma unroll
        for (int i = 0; i < 4; i++)
#pragma unroll
            for (int j = 0; j < 4; j++)
#pragma unroll
                for (int r = 0; r < 4; r++) {
                    int row = bm + mh * 64 + i * 16 + quad * 4 + r;
                    dst[(size_t)row * 1024 + n0 + j * 16 + c] = f2bf(acc[i][j][r]);
                }
    } else {                             // V: packed 8-B scatter (4 consecutive s)
#pragma unroll
        for (int i = 0; i < 4; i++) {
            int row0 = bm + mh * 64 + i * 16 + quad * 4;
            int b = row0 >> 11, s0v = row0 & 2047;
#pragma unroll
            for (int j = 0; j < 4; j++) {
                int col = n0 + j * 16 + c;
                int hh = col >> 6, dh = col & 63;
                short4v pk;
#pragma unroll
                for (int r = 0; r < 4; r++) pk[r] = (short)f2bf(acc[i][j][r]);
                *(short4v*)(vt + (size_t)((b * 16 + hh) * 64 + dh) * 2048 + s0v) = pk;
            }
        }
    }
}

// ----------------------------------------------------- output projection ---
__global__ __launch_bounds__(256, 4) void gemm_out(const ushort_t* __restrict__ A,
                                                   const ushort_t* __restrict__ Bt,
                                                   float* __restrict__ C) {
    const int K = 1024, N = 1024;
    int tid = threadIdx.x;
    int lane = tid & 63, w = tid >> 6;
    int c = lane & 15, quad = lane >> 4;
    int mh = w >> 1, nh = w & 1;
    int lin = blockIdx.y * gridDim.x + blockIdx.x;     // 512 blocks
    int xcd = lin & 7, idx = lin >> 3;
    int bm = ((xcd & 3) * 8 + (idx & 7)) * 128;
    int bn = ((xcd >> 2) * 8 + (idx >> 3)) * 64;
    int lr = lane >> 2, lq = lane & 3;

    __shared__ __align__(16) ushort_t As[16 * 512];
    __shared__ __align__(16) ushort_t Bs[8 * 512];

    const floatx4 zero = {0.f, 0.f, 0.f, 0.f};
    floatx4 acc[4][2];
#pragma unroll
    for (int i = 0; i < 4; i++)
#pragma unroll
        for (int j = 0; j < 2; j++) acc[i][j] = zero;

    for (int k0 = 0; k0 < K; k0 += 64) {
        __syncthreads();
#pragma unroll
        for (int ci = 0; ci < 6; ci++) {
            int ch = w * 6 + ci;              // 0..23, wave-uniform
            if (ch < 16) {
                int rg = ch >> 1, kc = ch & 1;
                async16(A + (size_t)(bm + rg * 16 + lr) * K + k0 + kc * 32 + lq * 8,
                        As + ch * 512);
            } else {
                int b2 = ch - 16;
                int rg = b2 >> 1, kc = b2 & 1;
                async16(Bt + (size_t)(bn + rg * 16 + lr) * K + k0 + kc * 32 + lq * 8,
                        Bs + b2 * 512);
            }
        }
        __syncthreads();
#pragma unroll
        for (int kc = 0; kc < 2; kc++) {
            short8 af[4], bf[2];
#pragma unroll
            for (int i = 0; i < 4; i++)
                af[i] = *(const short8*)(As + ((mh * 4 + i) * 2 + kc) * 512 + c * 32 + quad * 8);
#pragma unroll
            for (int j = 0; j < 2; j++)
                bf[j] = *(const short8*)(Bs + ((nh * 2 + j) * 2 + kc) * 512 + c * 32 + quad * 8);
#pragma unroll
            for (int i = 0; i < 4; i++)
#pragma unroll
                for (int j = 0; j < 2; j++)
                    acc[i][j] = __builtin_amdgcn_mfma_f32_16x16x32_bf16(af[i], bf[j], acc[i][j], 0, 0, 0);
        }
    }
#pragma unroll
    for (int i = 0; i < 4; i++)
#pragma unroll
        for (int j = 0; j < 2; j++)
#pragma unroll
            for (int r = 0; r < 4; r++) {
                int row = bm + mh * 64 + i * 16 + quad * 4 + r;
                int col = bn + nh * 32 + j * 16 + c;
                C[(size_t)row * N + col] = acc[i][j][r];
            }
}

// -------------------------------------------------------------- attention ---
// R10-verified layout + DOUBLE-BUFFERED K/V staging: one barrier per key-tile
// (each tile's async loads get a full tile-compute window before their drain).
// Grid (bh=32, pair=16) XCD-locality; uniform pairing (qt, 31-qt) = 33 tiles.
__global__ __launch_bounds__(256) void attn_kernel(const ushort_t* __restrict__ q,
                                                   const ushort_t* __restrict__ k,
                                                   const ushort_t* __restrict__ vt,
                                                   ushort_t* __restrict__ o) {
    int tid = threadIdx.x;
    int lane = tid & 63, w = tid >> 6;
    int c = lane & 15, quad = lane >> 4;
    int bh = blockIdx.x;
    int b = bh >> 4, h = bh & 15;
    int pair = blockIdx.y;              // 0..15
    int lr = lane >> 2, lq = lane & 3;
    const ushort_t* qb  = q + (size_t)b * 2048 * 1024 + h * 64;
    const ushort_t* kbp = k + (size_t)b * 2048 * 1024 + h * 64;
    const ushort_t* vtb = vt + (size_t)(b * 16 + h) * 64 * 2048;
    ushort_t* ob = o + (size_t)b * 2048 * 1024 + h * 64;

    __shared__ __align__(16) ushort_t Ks[2][8 * 512];
    __shared__ __align__(16) ushort_t Vs[2][8 * 512];
    __shared__ __align__(16) ushort_t Ps[64 * 72];

    const floatx4 zero = {0.f, 0.f, 0.f, 0.f};

#pragma unroll
    for (int g = 0; g < 2; g++) {
        int qt  = g ? (31 - pair) : pair;
        int t0b = qt * 64;
        int t0w = t0b + w * 16;
        int ntile = qt + 1;

        const ushort_t* qrow = qb + (size_t)(t0w + c) * 1024;
        short8 aq0 = *(const short8*)(qrow + quad * 8);
        short8 aq1 = *(const short8*)(qrow + 32 + quad * 8);

        float l_part[4];
        floatx4 oacc[4];
#pragma unroll
        for (int r = 0; r < 4; r++) l_part[r] = 0.f;
#pragma unroll
        for (int dt = 0; dt < 4; dt++) oacc[dt] = zero;

        __syncthreads();        // protect buffers from previous g's readers
        // prologue: stage tile 0 into buffer 0
#pragma unroll
        for (int ci = 0; ci < 4; ci++) {
            int ch = w * 4 + ci;
            if (ch < 8) {
                int nt = ch >> 1, hf = ch & 1;
                async16(kbp + (size_t)(nt * 16 + lr) * 1024 + hf * 32 + lq * 8,
                        Ks[0] + ch * 512);
            } else {
                int dt = (ch - 8) >> 1, hf = ch & 1;
                async16(vtb + (size_t)(dt * 16 + lr) * 2048 + hf * 32 + lq * 8,
                        Vs[0] + (ch - 8) * 512);
            }
        }

        for (int kt = 0; kt < ntile; kt++) {
            __syncthreads();    // drains tile kt's loads (compiler vmcnt(0)+barrier)
            int cur = kt & 1;
            if (kt + 1 < ntile) {
                int s1 = (kt + 1) * 64;
                int nxt = cur ^ 1;
#pragma unroll
                for (int ci = 0; ci < 4; ci++) {
                    int ch = w * 4 + ci;
                    if (ch < 8) {
                        int nt = ch >> 1, hf = ch & 1;
                        async16(kbp + (size_t)(s1 + nt * 16 + lr) * 1024 + hf * 32 + lq * 8,
                                Ks[nxt] + ch * 512);
                    } else {
                        int dt = (ch - 8) >> 1, hf = ch & 1;
                        async16(vtb + (size_t)(dt * 16 + lr) * 2048 + s1 + hf * 32 + lq * 8,
                                Vs[nxt] + (ch - 8) * 512);
                    }
                }
            }
            int s0 = kt * 64;

            floatx4 sacc[4];
#pragma unroll
            for (int nt = 0; nt < 4; nt++) sacc[nt] = zero;
#pragma unroll
            for (int nt = 0; nt < 4; nt++) {
                short8 b0 = *(const short8*)(Ks[cur] + nt * 1024 + c * 32 + quad * 8);
                short8 b1 = *(const short8*)(Ks[cur] + nt * 1024 + 512 + c * 32 + quad * 8);
                sacc[nt] = __builtin_amdgcn_mfma_f32_16x16x32_bf16(aq0, b0, sacc[nt], 0, 0, 0);
                sacc[nt] = __builtin_amdgcn_mfma_f32_16x16x32_bf16(aq1, b1, sacc[nt], 0, 0, 0);
            }

            if (kt == ntile - 1) {   // diagonal tile: causal mask
#pragma unroll
                for (int r = 0; r < 4; r++) {
                    int t = t0w + quad * 4 + r;
                    float ps = 0.f;
#pragma unroll
                    for (int nt = 0; nt < 4; nt++) {
                        float v = (s0 + nt * 16 + c > t) ? NEG_BIG : sacc[nt][r];
                        float e = __expf(v);
                        ps += e;
                        Ps[(w * 16 + quad * 4 + r) * 72 + nt * 16 + c] = f2bf(e);
                    }
                    l_part[r] += ps;
                }
            } else {
#pragma unroll
                for (int r = 0; r < 4; r++) {
                    float ps = 0.f;
#pragma unroll
                    for (int nt = 0; nt < 4; nt++) {
                        float e = __expf(sacc[nt][r]);
                        ps += e;
                        Ps[(w * 16 + quad * 4 + r) * 72 + nt * 16 + c] = f2bf(e);
                    }
                    l_part[r] += ps;
                }
            }

            short8 pa0 = *(const short8*)(Ps + (w * 16 + c) * 72 + quad * 8);
            short8 pa1 = *(const short8*)(Ps + (w * 16 + c) * 72 + 32 + quad * 8);
#pragma unroll
            for (int dt = 0; dt < 4; dt++) {
                short8 v0 = *(const short8*)(Vs[cur] + dt * 1024 + c * 32 + quad * 8);
                short8 v1 = *(const short8*)(Vs[cur] + dt * 1024 + 512 + c * 32 + quad * 8);
                oacc[dt] = __builtin_amdgcn_mfma_f32_16x16x32_bf16(pa0, v0, oacc[dt], 0, 0, 0);
                oacc[dt] = __builtin_amdgcn_mfma_f32_16x16x32_bf16(pa1, v1, oacc[dt], 0, 0, 0);
            }
        }

        float linv[4];
#pragma unroll
        for (int r = 0; r < 4; r++) {
            float l = l_part[r];
#pragma unroll
            for (int off = 1; off < 16; off <<= 1) l += __shfl_xor(l, off);
            linv[r] = 1.0f / l;
        }
#pragma unroll
        for (int dt = 0; dt < 4; dt++)
#pragma unroll
            for (int r = 0; r < 4; r++) {
                int t = t0w + quad * 4 + r;
                ob[(size_t)t * 1024 + dt * 16 + c] = f2bf(oacc[dt][r] * linv[r]);
            }
    }
}

// ------------------------------------------------------------------ launch ---
extern "C" void kernel_launch(void* const* d_in, const int* in_sizes, int n_in,
                              void* d_out, int out_size, void* d_ws, size_t ws_size,
                              hipStream_t stream) {
    const ushort_t* x  = (const ushort_t*)d_in[0];
    const ushort_t* g  = (const ushort_t*)d_in[1];
    const ushort_t* Wq = (const ushort_t*)d_in[2];
    const ushort_t* Wk = (const ushort_t*)d_in[3];
    const ushort_t* Wv = (const ushort_t*)d_in[4];
    const ushort_t* Wo = (const ushort_t*)d_in[5];

    char* ws = (char*)d_ws;
    const size_t MB = 1ull << 20;
    ushort_t* xn   = (ushort_t*)(ws);            // 8 MB (reused as attn out)
    ushort_t* qb   = (ushort_t*)(ws + 8 * MB);   // 8 MB
    ushort_t* kb   = (ushort_t*)(ws + 16 * MB);  // 8 MB
    ushort_t* vt   = (ushort_t*)(ws + 24 * MB);  // 8 MB ([b,h,dh,s])
    ushort_t* WTq3 = (ushort_t*)(ws + 32 * MB);  // 6 MB (q|k|v transposed)
    ushort_t* WoT  = (ushort_t*)(ws + 38 * MB);  // 2 MB  -> total 40 MB
    ushort_t* at   = xn;

    prep_kernel<<<dim3(32, 32, 8), dim3(32, 8), 0, stream>>>(Wq, Wk, Wv, Wo, WTq3, WoT, x, g, xn);

    gemm_qkv<<<dim3(24, 32), 256, 0, stream>>>(xn, WTq3, qb, kb, vt);

    attn_kernel<<<dim3(32, 16), 256, 0, stream>>>(qb, kb, vt, at);

    gemm_out<<<dim3(16, 32), 256, 0, stream>>>(at, WoT, (float*)d_out);
}

// Round 13
// 185.526 us; speedup vs baseline: 1.5779x; 1.0094x over previous
//
#include <hip/hip_runtime.h>

typedef unsigned short ushort_t;
typedef __attribute__((ext_vector_type(8))) short short8;   // 8 bf16 (4 VGPRs)
typedef __attribute__((ext_vector_type(4))) short short4v;  // 4 bf16 (8 B)
typedef __attribute__((ext_vector_type(4))) float floatx4;  // 4 fp32 acc

#define DEV static __device__ __forceinline__
#define NEG_BIG (-1e30f)

typedef const __attribute__((address_space(1))) unsigned int* gas_ptr;
typedef __attribute__((address_space(3))) unsigned int* las_ptr;

// async global->LDS, 16B per lane; LDS dest = base + lane*16 (wave-uniform base)
DEV void async16(const ushort_t* g, ushort_t* l) {
    __builtin_amdgcn_global_load_lds((gas_ptr)(const void*)g, (las_ptr)(void*)l, 16, 0, 0);
}

DEV float bf2f(ushort_t u) {
    union { unsigned u; float f; } v; v.u = ((unsigned)u) << 16; return v.f;
}
DEV ushort_t f2bf(float f) {            // RNE — for values feeding long chains
    union { float f; unsigned u; } v; v.f = f;
    unsigned r = v.u + 0x7FFF + ((v.u >> 16) & 1);
    return (ushort_t)(r >> 16);
}
DEV ushort_t f2bf_trunc(float f) {      // 1-op truncation — P / O only (R13)
    union { float f; unsigned u; } v; v.f = f;
    return (ushort_t)(v.u >> 16);
}
DEV float load_bf16_scrub(const ushort_t* p, size_t i) {
    ushort_t u = p[i];
    if (((u >> 7) & 0xFF) == 0xFF) u = 0;
    return bf2f(u);
}
DEV float load_f32_scrub(const ushort_t* p, size_t i) {
    unsigned u = ((const unsigned*)p)[i];
    if (((u >> 23) & 0xFF) == 0xFF) u = 0;
    union { unsigned u; float f; } v; v.u = u; return v.f;
}

// Probe: fp32 vs bf16 raw data (proven in R3/R4). Block-uniform result.
DEV int probe_is_f32(const ushort_t* __restrict__ p) {
    int tid = threadIdx.x + threadIdx.y * blockDim.x;
    int nthr = blockDim.x * blockDim.y;
    __shared__ int cnt;
    if (tid == 0) cnt = 0;
    __syncthreads();
    int weird = 0;
    for (int i = tid; i < 2048; i += nthr) {
        unsigned e = (p[i] >> 7) & 0xFF;
        weird += (e >= 0x90) ? 1 : 0;
    }
#pragma unroll
    for (int off = 32; off; off >>= 1) weird += __shfl_xor(weird, off);
    if ((tid & 63) == 0) atomicAdd(&cnt, weird);
    __syncthreads();
    return cnt > 16;
}

// ----------------------------------------------- fused prep (1 launch) ------
__global__ void prep_kernel(const ushort_t* __restrict__ W0,
                            const ushort_t* __restrict__ W1,
                            const ushort_t* __restrict__ W2,
                            const ushort_t* __restrict__ W3,
                            ushort_t* __restrict__ WTq3,
                            ushort_t* __restrict__ WoT,
                            const ushort_t* __restrict__ x,
                            const ushort_t* __restrict__ g,
                            ushort_t* __restrict__ xn) {
    int is_f32 = probe_is_f32(x);
    int z = blockIdx.z;
    if (z < 4) {
        const ushort_t* W = (z == 0) ? W0 : (z == 1) ? W1 : (z == 2) ? W2 : W3;
        __shared__ ushort_t tile[32][33];
        int tx = threadIdx.x, ty = threadIdx.y;
        int xx = blockIdx.x * 32 + tx;      // n
        int y0 = blockIdx.y * 32;           // k
#pragma unroll
        for (int j = 0; j < 32; j += 8) {
            size_t idx = (size_t)(y0 + ty + j) * 1024 + xx;
            tile[ty + j][tx] = f2bf(is_f32 ? load_f32_scrub(W, idx) : load_bf16_scrub(W, idx));
        }
        __syncthreads();
        int nx = blockIdx.y * 32 + tx;
        ushort_t* dst = (z < 3) ? WTq3 : WoT;
        int ny0 = blockIdx.x * 32 + ((z < 3) ? z * 1024 : 0);
#pragma unroll
        for (int j = 0; j < 32; j += 8)
            dst[(size_t)(ny0 + ty + j) * 1024 + nx] = tile[tx][ty + j];
    } else {
        int row = (z - 4) * 1024 + blockIdx.y * 32 + blockIdx.x;
        int tid = threadIdx.y * 32 + threadIdx.x;
        float vals[4], gv[4];
        size_t base = (size_t)row * 1024 + tid * 4;
#pragma unroll
        for (int i = 0; i < 4; i++) {
            if (is_f32) {
                vals[i] = load_f32_scrub(x, base + i);
                gv[i]   = load_f32_scrub(g, tid * 4 + i);
            } else {
                vals[i] = load_bf16_scrub(x, base + i);
                gv[i]   = load_bf16_scrub(g, tid * 4 + i);
            }
        }
        float ss = vals[0]*vals[0] + vals[1]*vals[1] + vals[2]*vals[2] + vals[3]*vals[3];
#pragma unroll
        for (int off = 32; off > 0; off >>= 1) ss += __shfl_xor(ss, off);
        __shared__ float red[4];
        if ((tid & 63) == 0) red[tid >> 6] = ss;
        __syncthreads();
        ss = red[0] + red[1] + red[2] + red[3];
        float inv = rsqrtf(ss * (1.0f / 1024.0f) + 1e-6f);
#pragma unroll
        for (int i = 0; i < 4; i++)
            xn[base + i] = f2bf(vals[i] * inv * gv[i]);
    }
}

// ------------------------------------------------------- fused QKV GEMM ----
// 128x128 tile, BK=64, COALESCED async staging (R8/R10-verified; R9 proved
// bank conflicts benign / coalescing binding). XCD-region swizzle.
// Epilogue: fast-math RoPE (__sinf/__cosf), q pre-scaled 1/8, packed V scatter.
__global__ __launch_bounds__(256, 4) void gemm_qkv(const ushort_t* __restrict__ A,
                                                   const ushort_t* __restrict__ Bt,
                                                   ushort_t* __restrict__ qb,
                                                   ushort_t* __restrict__ kb,
                                                   ushort_t* __restrict__ vt) {
    const int K = 1024;
    int tid = threadIdx.x;
    int lane = tid & 63, w = tid >> 6;
    int c = lane & 15, quad = lane >> 4;
    int mh = w >> 1, nh = w & 1;
    int lin = blockIdx.y * gridDim.x + blockIdx.x;     // 768 blocks
    int xcd = lin & 7, idx = lin >> 3;
    int bm = ((xcd & 3) * 8 + (idx & 7)) * 128;        // m-block in [0,32)
    int bn = ((xcd >> 2) * 12 + (idx >> 3)) * 128;     // n-block in [0,24)
    int lr = lane >> 2, lq = lane & 3;                 // staging lane map

    __shared__ __align__(16) ushort_t As[16 * 512];    // 16 KB
    __shared__ __align__(16) ushort_t Bs[16 * 512];    // 16 KB

    const floatx4 zero = {0.f, 0.f, 0.f, 0.f};
    floatx4 acc[4][4];
#pragma unroll
    for (int i = 0; i < 4; i++)
#pragma unroll
        for (int j = 0; j < 4; j++) acc[i][j] = zero;

    for (int k0 = 0; k0 < K; k0 += 64) {
        __syncthreads();
#pragma unroll
        for (int ci = 0; ci < 8; ci++) {
            int ch = w * 8 + ci;              // 0..31, wave-uniform
            if (ch < 16) {
                int rg = ch >> 1, kc = ch & 1;
                async16(A + (size_t)(bm + rg * 16 + lr) * K + k0 + kc * 32 + lq * 8,
                        As + ch * 512);
            } else {
                int b2 = ch - 16;
                int rg = b2 >> 1, kc = b2 & 1;
                async16(Bt + (size_t)(bn + rg * 16 + lr) * K + k0 + kc * 32 + lq * 8,
                        Bs + b2 * 512);
            }
        }
        __syncthreads();
#pragma unroll
        for (int kc = 0; kc < 2; kc++) {
            short8 af[4], bf[4];
#pragma unroll
            for (int i = 0; i < 4; i++)
                af[i] = *(const short8*)(As + ((mh * 4 + i) * 2 + kc) * 512 + c * 32 + quad * 8);
#pragma unroll
            for (int j = 0; j < 4; j++)
                bf[j] = *(const short8*)(Bs + ((nh * 4 + j) * 2 + kc) * 512 + c * 32 + quad * 8);
#pragma unroll
            for (int i = 0; i < 4; i++)
#pragma unroll
                for (int j = 0; j < 4; j++)
                    acc[i][j] = __builtin_amdgcn_mfma_f32_16x16x32_bf16(af[i], bf[j], acc[i][j], 0, 0, 0);
        }
    }

    int proj = bn >> 10;                 // 0=q, 1=k, 2=v (blocks never straddle)
    int n0 = (bn & 1023) + nh * 64;
    if (proj < 2) {                      // RoPE: d = j*16+c, pairs (j, j+2)
        float th0 = exp2f((float)c * (-19.931568569324174f / 32.0f));
        float th1 = exp2f((float)(16 + c) * (-19.931568569324174f / 32.0f));
        float scale = (proj == 0) ? 0.125f : 1.0f;
#pragma unroll
        for (int i = 0; i < 4; i++)
#pragma unroll
            for (int r = 0; r < 4; r++) {
                int s = (bm + mh * 64 + i * 16 + quad * 4 + r) & 2047;
                float a0 = (float)s * th0, a1 = (float)s * th1;
                float sn0 = __sinf(a0), cs0 = __cosf(a0);
                float sn1 = __sinf(a1), cs1 = __cosf(a1);
                float x1a = acc[i][0][r], x2a = acc[i][2][r];
                acc[i][0][r] = (x1a * cs0 - x2a * sn0) * scale;
                acc[i][2][r] = (x1a * sn0 + x2a * cs0) * scale;
                float x1b = acc[i][1][r], x2b = acc[i][3][r];
                acc[i][1][r] = (x1b * cs1 - x2b * sn1) * scale;
                acc[i][3][r] = (x1b * sn1 + x2b * cs1) * scale;
            }
        ushort_t* dst = (proj == 0) ? qb : kb;
#pragma unroll
        for (int i = 0; i < 4; i++)
#pragma unroll
            for (int j = 0; j < 4; j++)
#pragma unroll
                for (int r = 0; r < 4; r++) {
                    int row = bm + mh * 64 + i * 16 + quad * 4 + r;
                    dst[(size_t)row * 1024 + n0 + j * 16 + c] = f2bf(acc[i][j][r]);
                }
    } else {                             // V: packed 8-B scatter (4 consecutive s)
#pragma unroll
        for (int i = 0; i < 4; i++) {
            int row0 = bm + mh * 64 + i * 16 + quad * 4;
            int b = row0 >> 11, s0v = row0 & 2047;
#pragma unroll
            for (int j = 0; j < 4; j++) {
                int col = n0 + j * 16 + c;
                int hh = col >> 6, dh = col & 63;
                short4v pk;
#pragma unroll
                for (int r = 0; r < 4; r++) pk[r] = (short)f2bf(acc[i][j][r]);
                *(short4v*)(vt + (size_t)((b * 16 + hh) * 64 + dh) * 2048 + s0v) = pk;
            }
        }
    }
}

// ----------------------------------------------------- output projection ---
__global__ __launch_bounds__(256, 4) void gemm_out(const ushort_t* __restrict__ A,
                                                   const ushort_t* __restrict__ Bt,
                                                   float* __restrict__ C) {
    const int K = 1024, N = 1024;
    int tid = threadIdx.x;
    int lane = tid & 63, w = tid >> 6;
    int c = lane & 15, quad = lane >> 4;
    int mh = w >> 1, nh = w & 1;
    int lin = blockIdx.y * gridDim.x + blockIdx.x;     // 512 blocks
    int xcd = lin & 7, idx = lin >> 3;
    int bm = ((xcd & 3) * 8 + (idx & 7)) * 128;
    int bn = ((xcd >> 2) * 8 + (idx >> 3)) * 64;
    int lr = lane >> 2, lq = lane & 3;

    __shared__ __align__(16) ushort_t As[16 * 512];
    __shared__ __align__(16) ushort_t Bs[8 * 512];

    const floatx4 zero = {0.f, 0.f, 0.f, 0.f};
    floatx4 acc[4][2];
#pragma unroll
    for (int i = 0; i < 4; i++)
#pragma unroll
        for (int j = 0; j < 2; j++) acc[i][j] = zero;

    for (int k0 = 0; k0 < K; k0 += 64) {
        __syncthreads();
#pragma unroll
        for (int ci = 0; ci < 6; ci++) {
            int ch = w * 6 + ci;              // 0..23, wave-uniform
            if (ch < 16) {
                int rg = ch >> 1, kc = ch & 1;
                async16(A + (size_t)(bm + rg * 16 + lr) * K + k0 + kc * 32 + lq * 8,
                        As + ch * 512);
            } else {
                int b2 = ch - 16;
                int rg = b2 >> 1, kc = b2 & 1;
                async16(Bt + (size_t)(bn + rg * 16 + lr) * K + k0 + kc * 32 + lq * 8,
                        Bs + b2 * 512);
            }
        }
        __syncthreads();
#pragma unroll
        for (int kc = 0; kc < 2; kc++) {
            short8 af[4], bf[2];
#pragma unroll
            for (int i = 0; i < 4; i++)
                af[i] = *(const short8*)(As + ((mh * 4 + i) * 2 + kc) * 512 + c * 32 + quad * 8);
#pragma unroll
            for (int j = 0; j < 2; j++)
                bf[j] = *(const short8*)(Bs + ((nh * 2 + j) * 2 + kc) * 512 + c * 32 + quad * 8);
#pragma unroll
            for (int i = 0; i < 4; i++)
#pragma unroll
                for (int j = 0; j < 2; j++)
                    acc[i][j] = __builtin_amdgcn_mfma_f32_16x16x32_bf16(af[i], bf[j], acc[i][j], 0, 0, 0);
        }
    }
#pragma unroll
    for (int i = 0; i < 4; i++)
#pragma unroll
        for (int j = 0; j < 2; j++)
#pragma unroll
            for (int r = 0; r < 4; r++) {
                int row = bm + mh * 64 + i * 16 + quad * 4 + r;
                int col = bn + nh * 32 + j * 16 + c;
                C[(size_t)row * N + col] = acc[i][j][r];
            }
}

// -------------------------------------------------------------- attention ---
// R13: ONE q-tile (64 rows) per block, grid (bh=32, 32), qt = 31-blockIdx.y
// so heaviest blocks dispatch first; 1024 blocks, 3 blocks/CU (LDS cap) —
// +50% resident waves vs R12's 2/CU pairing. Same-bh blocks share lin%8 ->
// XCD K/V locality kept. Double-buffered K/V staging; trunc-P (1-op bf16).
__global__ __launch_bounds__(256) void attn_kernel(const ushort_t* __restrict__ q,
                                                   const ushort_t* __restrict__ k,
                                                   const ushort_t* __restrict__ vt,
                                                   ushort_t* __restrict__ o) {
    int tid = threadIdx.x;
    int lane = tid & 63, w = tid >> 6;
    int c = lane & 15, quad = lane >> 4;
    int bh = blockIdx.x;
    int b = bh >> 4, h = bh & 15;
    int qt = 31 - (int)blockIdx.y;      // heaviest (qt=31) first
    int lr = lane >> 2, lq = lane & 3;
    const ushort_t* qb  = q + (size_t)b * 2048 * 1024 + h * 64;
    const ushort_t* kbp = k + (size_t)b * 2048 * 1024 + h * 64;
    const ushort_t* vtb = vt + (size_t)(b * 16 + h) * 64 * 2048;
    ushort_t* ob = o + (size_t)b * 2048 * 1024 + h * 64;

    __shared__ __align__(16) ushort_t Ks[2][8 * 512];
    __shared__ __align__(16) ushort_t Vs[2][8 * 512];
    __shared__ __align__(16) ushort_t Ps[64 * 72];

    const floatx4 zero = {0.f, 0.f, 0.f, 0.f};

    int t0b = qt * 64;
    int t0w = t0b + w * 16;
    int ntile = qt + 1;

    const ushort_t* qrow = qb + (size_t)(t0w + c) * 1024;
    short8 aq0 = *(const short8*)(qrow + quad * 8);
    short8 aq1 = *(const short8*)(qrow + 32 + quad * 8);

    float l_part[4];
    floatx4 oacc[4];
#pragma unroll
    for (int r = 0; r < 4; r++) l_part[r] = 0.f;
#pragma unroll
    for (int dt = 0; dt < 4; dt++) oacc[dt] = zero;

    // prologue: stage tile 0 into buffer 0
#pragma unroll
    for (int ci = 0; ci < 4; ci++) {
        int ch = w * 4 + ci;
        if (ch < 8) {
            int nt = ch >> 1, hf = ch & 1;
            async16(kbp + (size_t)(nt * 16 + lr) * 1024 + hf * 32 + lq * 8,
                    Ks[0] + ch * 512);
        } else {
            int dt = (ch - 8) >> 1, hf = ch & 1;
            async16(vtb + (size_t)(dt * 16 + lr) * 2048 + hf * 32 + lq * 8,
                    Vs[0] + (ch - 8) * 512);
        }
    }

    for (int kt = 0; kt < ntile; kt++) {
        __syncthreads();    // drains tile kt's loads
        int cur = kt & 1;
        if (kt + 1 < ntile) {
            int s1 = (kt + 1) * 64;
            int nxt = cur ^ 1;
#pragma unroll
            for (int ci = 0; ci < 4; ci++) {
                int ch = w * 4 + ci;
                if (ch < 8) {
                    int nt = ch >> 1, hf = ch & 1;
                    async16(kbp + (size_t)(s1 + nt * 16 + lr) * 1024 + hf * 32 + lq * 8,
                            Ks[nxt] + ch * 512);
                } else {
                    int dt = (ch - 8) >> 1, hf = ch & 1;
                    async16(vtb + (size_t)(dt * 16 + lr) * 2048 + s1 + hf * 32 + lq * 8,
                            Vs[nxt] + (ch - 8) * 512);
                }
            }
        }
        int s0 = kt * 64;

        floatx4 sacc[4];
#pragma unroll
        for (int nt = 0; nt < 4; nt++) sacc[nt] = zero;
#pragma unroll
        for (int nt = 0; nt < 4; nt++) {
            short8 b0 = *(const short8*)(Ks[cur] + nt * 1024 + c * 32 + quad * 8);
            short8 b1 = *(const short8*)(Ks[cur] + nt * 1024 + 512 + c * 32 + quad * 8);
            sacc[nt] = __builtin_amdgcn_mfma_f32_16x16x32_bf16(aq0, b0, sacc[nt], 0, 0, 0);
            sacc[nt] = __builtin_amdgcn_mfma_f32_16x16x32_bf16(aq1, b1, sacc[nt], 0, 0, 0);
        }

        if (kt == ntile - 1) {   // diagonal tile: causal mask
#pragma unroll
            for (int r = 0; r < 4; r++) {
                int t = t0w + quad * 4 + r;
                float ps = 0.f;
#pragma unroll
                for (int nt = 0; nt < 4; nt++) {
                    float v = (s0 + nt * 16 + c > t) ? NEG_BIG : sacc[nt][r];
                    float e = __expf(v);
                    ps += e;
                    Ps[(w * 16 + quad * 4 + r) * 72 + nt * 16 + c] = f2bf_trunc(e);
                }
                l_part[r] += ps;
            }
        } else {
#pragma unroll
            for (int r = 0; r < 4; r++) {
                float ps = 0.f;
#pragma unroll
                for (int nt = 0; nt < 4; nt++) {
                    float e = __expf(sacc[nt][r]);
                    ps += e;
                    Ps[(w * 16 + quad * 4 + r) * 72 + nt * 16 + c] = f2bf_trunc(e);
                }
                l_part[r] += ps;
            }
        }

        short8 pa0 = *(const short8*)(Ps + (w * 16 + c) * 72 + quad * 8);
        short8 pa1 = *(const short8*)(Ps + (w * 16 + c) * 72 + 32 + quad * 8);
#pragma unroll
        for (int dt = 0; dt < 4; dt++) {
            short8 v0 = *(const short8*)(Vs[cur] + dt * 1024 + c * 32 + quad * 8);
            short8 v1 = *(const short8*)(Vs[cur] + dt * 1024 + 512 + c * 32 + quad * 8);
            oacc[dt] = __builtin_amdgcn_mfma_f32_16x16x32_bf16(pa0, v0, oacc[dt], 0, 0, 0);
            oacc[dt] = __builtin_amdgcn_mfma_f32_16x16x32_bf16(pa1, v1, oacc[dt], 0, 0, 0);
        }
    }

    float linv[4];
#pragma unroll
    for (int r = 0; r < 4; r++) {
        float l = l_part[r];
#pragma unroll
        for (int off = 1; off < 16; off <<= 1) l += __shfl_xor(l, off);
        linv[r] = 1.0f / l;
    }
#pragma unroll
    for (int dt = 0; dt < 4; dt++)
#pragma unroll
        for (int r = 0; r < 4; r++) {
            int t = t0w + quad * 4 + r;
            ob[(size_t)t * 1024 + dt * 16 + c] = f2bf_trunc(oacc[dt][r] * linv[r]);
        }
}

// ------------------------------------------------------------------ launch ---
extern "C" void kernel_launch(void* const* d_in, const int* in_sizes, int n_in,
                              void* d_out, int out_size, void* d_ws, size_t ws_size,
                              hipStream_t stream) {
    const ushort_t* x  = (const ushort_t*)d_in[0];
    const ushort_t* g  = (const ushort_t*)d_in[1];
    const ushort_t* Wq = (const ushort_t*)d_in[2];
    const ushort_t* Wk = (const ushort_t*)d_in[3];
    const ushort_t* Wv = (const ushort_t*)d_in[4];
    const ushort_t* Wo = (const ushort_t*)d_in[5];

    char* ws = (char*)d_ws;
    const size_t MB = 1ull << 20;
    ushort_t* xn   = (ushort_t*)(ws);            // 8 MB (reused as attn out)
    ushort_t* qb   = (ushort_t*)(ws + 8 * MB);   // 8 MB
    ushort_t* kb   = (ushort_t*)(ws + 16 * MB);  // 8 MB
    ushort_t* vt   = (ushort_t*)(ws + 24 * MB);  // 8 MB ([b,h,dh,s])
    ushort_t* WTq3 = (ushort_t*)(ws + 32 * MB);  // 6 MB (q|k|v transposed)
    ushort_t* WoT  = (ushort_t*)(ws + 38 * MB);  // 2 MB  -> total 40 MB
    ushort_t* at   = xn;

    prep_kernel<<<dim3(32, 32, 8), dim3(32, 8), 0, stream>>>(Wq, Wk, Wv, Wo, WTq3, WoT, x, g, xn);

    gemm_qkv<<<dim3(24, 32), 256, 0, stream>>>(xn, WTq3, qb, kb, vt);

    attn_kernel<<<dim3(32, 32), 256, 0, stream>>>(qb, kb, vt, at);

    gemm_out<<<dim3(16, 32), 256, 0, stream>>>(at, WoT, (float*)d_out);
}